// Round 1
// baseline (1920.329 us; speedup 1.0000x reference)
//
#include <hip/hip_runtime.h>
#include <math.h>

#define HIDDEN 1024
#define SEQ    2048
#define NHEAD  16
#define HDIM   64

// ---------------------------------------------------------------------------
// LayerNorm: one block per row (1024 floats), 256 threads x 4 elems.
// ---------------------------------------------------------------------------
__global__ __launch_bounds__(256) void ln_kernel(const float* __restrict__ x,
                                                 const float* __restrict__ g,
                                                 const float* __restrict__ beta,
                                                 float* __restrict__ out) {
    int row = blockIdx.x;
    int tid = threadIdx.x;
    const float* xr = x + (size_t)row * HIDDEN;
    float4 v = *(const float4*)(xr + tid * 4);
    float s  = v.x + v.y + v.z + v.w;
    float s2 = v.x * v.x + v.y * v.y + v.z * v.z + v.w * v.w;
#pragma unroll
    for (int off = 1; off < 64; off <<= 1) {
        s  += __shfl_xor(s, off, 64);
        s2 += __shfl_xor(s2, off, 64);
    }
    __shared__ float red[8];
    int wid = tid >> 6;
    if ((tid & 63) == 0) { red[wid] = s; red[wid + 4] = s2; }
    __syncthreads();
    s  = red[0] + red[1] + red[2] + red[3];
    s2 = red[4] + red[5] + red[6] + red[7];
    float mu  = s * (1.0f / HIDDEN);
    float var = fmaxf(s2 * (1.0f / HIDDEN) - mu * mu, 0.0f);
    float inv = rsqrtf(var + 1e-5f);
    float4 gv = *(const float4*)(g + tid * 4);
    float4 bv = *(const float4*)(beta + tid * 4);
    float4 o;
    o.x = (v.x - mu) * inv * gv.x + bv.x;
    o.y = (v.y - mu) * inv * gv.y + bv.y;
    o.z = (v.z - mu) * inv * gv.z + bv.z;
    o.w = (v.w - mu) * inv * gv.w + bv.w;
    *(float4*)(out + (size_t)row * HIDDEN + tid * 4) = o;
}

// ---------------------------------------------------------------------------
// fp32 GEMM core: C[M,N] = A[M,K]*B[K,N] (+bias)(+relu)(+residual)
// 128x128 block tile, 8x8 per thread, K-tile 16. A staged transposed in LDS.
// ---------------------------------------------------------------------------
template <bool BIAS, bool RELU, bool RES>
__device__ __forceinline__ void gemm_core(const float* __restrict__ A,
                                          const float* __restrict__ B,
                                          const float* __restrict__ bias,
                                          const float* __restrict__ res,
                                          float* __restrict__ C,
                                          int M, int N, int K, int m0, int n0) {
    __shared__ float Ast[16][132];   // [k][m]
    __shared__ float Bst[16][132];   // [k][n]
    int tid = threadIdx.x;
    int tx = tid & 15, ty = tid >> 4;
    int am = tid >> 1;            // 0..127
    int ak = (tid & 1) * 8;       // 0 or 8
    int bk = tid >> 4;            // 0..15
    int bn = (tid & 15) * 8;      // 0..120

    float acc[8][8];
#pragma unroll
    for (int i = 0; i < 8; i++)
#pragma unroll
        for (int j = 0; j < 8; j++) acc[i][j] = 0.0f;

    for (int k0 = 0; k0 < K; k0 += 16) {
        float4 a0 = *(const float4*)(A + (size_t)(m0 + am) * K + k0 + ak);
        float4 a1 = *(const float4*)(A + (size_t)(m0 + am) * K + k0 + ak + 4);
        float4 b0 = *(const float4*)(B + (size_t)(k0 + bk) * N + n0 + bn);
        float4 b1 = *(const float4*)(B + (size_t)(k0 + bk) * N + n0 + bn + 4);
        Ast[ak + 0][am] = a0.x; Ast[ak + 1][am] = a0.y;
        Ast[ak + 2][am] = a0.z; Ast[ak + 3][am] = a0.w;
        Ast[ak + 4][am] = a1.x; Ast[ak + 5][am] = a1.y;
        Ast[ak + 6][am] = a1.z; Ast[ak + 7][am] = a1.w;
        *(float4*)&Bst[bk][bn]     = b0;
        *(float4*)&Bst[bk][bn + 4] = b1;
        __syncthreads();
#pragma unroll
        for (int kk = 0; kk < 16; kk++) {
            float4 av0 = *(const float4*)&Ast[kk][ty * 8];
            float4 av1 = *(const float4*)&Ast[kk][ty * 8 + 4];
            float4 bv0 = *(const float4*)&Bst[kk][tx * 8];
            float4 bv1 = *(const float4*)&Bst[kk][tx * 8 + 4];
            float a[8] = {av0.x, av0.y, av0.z, av0.w, av1.x, av1.y, av1.z, av1.w};
            float b[8] = {bv0.x, bv0.y, bv0.z, bv0.w, bv1.x, bv1.y, bv1.z, bv1.w};
#pragma unroll
            for (int i = 0; i < 8; i++)
#pragma unroll
                for (int j = 0; j < 8; j++)
                    acc[i][j] = fmaf(a[i], b[j], acc[i][j]);
        }
        __syncthreads();
    }

#pragma unroll
    for (int i = 0; i < 8; i++) {
        int m = m0 + ty * 8 + i;
#pragma unroll
        for (int jv = 0; jv < 2; jv++) {
            int n = n0 + tx * 8 + jv * 4;
            float4 c;
            c.x = acc[i][jv * 4 + 0]; c.y = acc[i][jv * 4 + 1];
            c.z = acc[i][jv * 4 + 2]; c.w = acc[i][jv * 4 + 3];
            if (BIAS) {
                float4 bb = *(const float4*)(bias + n);
                c.x += bb.x; c.y += bb.y; c.z += bb.z; c.w += bb.w;
            }
            if (RELU) {
                c.x = fmaxf(c.x, 0.0f); c.y = fmaxf(c.y, 0.0f);
                c.z = fmaxf(c.z, 0.0f); c.w = fmaxf(c.w, 0.0f);
            }
            if (RES) {
                float4 rr = *(const float4*)(res + (size_t)m * N + n);
                c.x += rr.x; c.y += rr.y; c.z += rr.z; c.w += rr.w;
            }
            *(float4*)(C + (size_t)m * N + n) = c;
        }
    }
}

template <bool BIAS, bool RELU, bool RES>
__global__ __launch_bounds__(256) void gemm_kernel(const float* __restrict__ A,
                                                   const float* __restrict__ B,
                                                   const float* __restrict__ bias,
                                                   const float* __restrict__ res,
                                                   float* __restrict__ C,
                                                   int M, int N, int K) {
    gemm_core<BIAS, RELU, RES>(A, B, bias, res, C, M, N, K,
                               blockIdx.y * 128, blockIdx.x * 128);
}

// QKV fused via blockIdx.z (3 blocks/CU for latency hiding)
__global__ __launch_bounds__(256) void gemm_qkv_kernel(const float* __restrict__ h,
                                                       const float* __restrict__ Wq,
                                                       const float* __restrict__ Wk,
                                                       const float* __restrict__ Wv,
                                                       float* __restrict__ q,
                                                       float* __restrict__ k,
                                                       float* __restrict__ v) {
    const float* B = (blockIdx.z == 0) ? Wq : (blockIdx.z == 1) ? Wk : Wv;
    float* C = (blockIdx.z == 0) ? q : (blockIdx.z == 1) ? k : v;
    gemm_core<false, false, false>(h, B, nullptr, nullptr, C,
                                   2 * SEQ, HIDDEN, HIDDEN,
                                   blockIdx.y * 128, blockIdx.x * 128);
}

// ---------------------------------------------------------------------------
// Flash-style causal attention, fp32. Q-tile 64, K-tile 64.
// Threads (16 ty x 16 tx), 4x4 register block. Q,K stored transposed [d][r]
// in LDS; P^T overlays K's buffer.  q/k/v layout: [B*T, NH*HD].
// ---------------------------------------------------------------------------
__global__ __launch_bounds__(256) void attn_kernel(const float* __restrict__ Q,
                                                   const float* __restrict__ Kb,
                                                   const float* __restrict__ Vb,
                                                   float* __restrict__ ctx) {
    __shared__ float Qst[64][68];    // [d][r]
    __shared__ float KPst[64][68];   // K phase: [d][s];  P phase: [s][r]
    __shared__ float Vs[64][68];     // [s][d]

    int bh = blockIdx.x;             // 0..31
    int qt = blockIdx.y;             // 0..31
    int b = bh >> 4, h = bh & 15;
    int tid = threadIdx.x;
    int tx = tid & 15, ty = tid >> 4;

    const float* Qp = Q + ((size_t)(b * SEQ + qt * 64)) * HIDDEN + h * HDIM;
    {
        int r = tid >> 2;
        int dseg = (tid & 3) * 16;
#pragma unroll
        for (int i = 0; i < 4; i++) {
            float4 t4 = *(const float4*)(Qp + (size_t)r * HIDDEN + dseg + i * 4);
            Qst[dseg + i * 4 + 0][r] = t4.x;
            Qst[dseg + i * 4 + 1][r] = t4.y;
            Qst[dseg + i * 4 + 2][r] = t4.z;
            Qst[dseg + i * 4 + 3][r] = t4.w;
        }
    }

    float m_i[4], l_i[4], o_acc[4][4];
#pragma unroll
    for (int i = 0; i < 4; i++) {
        m_i[i] = -INFINITY; l_i[i] = 0.0f;
#pragma unroll
        for (int j = 0; j < 4; j++) o_acc[i][j] = 0.0f;
    }
    int qrow0 = qt * 64;

    for (int kt = 0; kt <= qt; kt++) {
        __syncthreads();   // prev-iter LDS reads done (also covers Q stores)
        {
            const float* Kp = Kb + ((size_t)(b * SEQ + kt * 64)) * HIDDEN + h * HDIM;
            const float* Vp = Vb + ((size_t)(b * SEQ + kt * 64)) * HIDDEN + h * HDIM;
            int s = tid >> 2;
            int dseg = (tid & 3) * 16;
#pragma unroll
            for (int i = 0; i < 4; i++) {
                float4 k4 = *(const float4*)(Kp + (size_t)s * HIDDEN + dseg + i * 4);
                KPst[dseg + i * 4 + 0][s] = k4.x;
                KPst[dseg + i * 4 + 1][s] = k4.y;
                KPst[dseg + i * 4 + 2][s] = k4.z;
                KPst[dseg + i * 4 + 3][s] = k4.w;
                float4 v4 = *(const float4*)(Vp + (size_t)s * HIDDEN + dseg + i * 4);
                *(float4*)&Vs[s][dseg + i * 4] = v4;
            }
        }
        __syncthreads();

        // scores S = Q K^T   (4x4 per thread)
        float sc[4][4];
#pragma unroll
        for (int i = 0; i < 4; i++)
#pragma unroll
            for (int j = 0; j < 4; j++) sc[i][j] = 0.0f;
#pragma unroll 16
        for (int d = 0; d < 64; d++) {
            float4 q4 = *(const float4*)&Qst[d][ty * 4];
            float4 k4 = *(const float4*)&KPst[d][tx * 4];
            float qa[4] = {q4.x, q4.y, q4.z, q4.w};
            float ka[4] = {k4.x, k4.y, k4.z, k4.w};
#pragma unroll
            for (int i = 0; i < 4; i++)
#pragma unroll
                for (int j = 0; j < 4; j++)
                    sc[i][j] = fmaf(qa[i], ka[j], sc[i][j]);
        }

        // online softmax (rows reduce across the 16 tx lanes)
#pragma unroll
        for (int i = 0; i < 4; i++) {
            int r = qrow0 + ty * 4 + i;
            float rmax = -INFINITY;
#pragma unroll
            for (int j = 0; j < 4; j++) {
                int s = kt * 64 + tx * 4 + j;
                sc[i][j] = (s <= r) ? sc[i][j] * 0.125f : -INFINITY;
                rmax = fmaxf(rmax, sc[i][j]);
            }
            rmax = fmaxf(rmax, __shfl_xor(rmax, 1, 64));
            rmax = fmaxf(rmax, __shfl_xor(rmax, 2, 64));
            rmax = fmaxf(rmax, __shfl_xor(rmax, 4, 64));
            rmax = fmaxf(rmax, __shfl_xor(rmax, 8, 64));
            float mnew = fmaxf(m_i[i], rmax);
            float alpha = __expf(m_i[i] - mnew);
            float psum = 0.0f;
#pragma unroll
            for (int j = 0; j < 4; j++) {
                sc[i][j] = __expf(sc[i][j] - mnew);
                psum += sc[i][j];
            }
            psum += __shfl_xor(psum, 1, 64);
            psum += __shfl_xor(psum, 2, 64);
            psum += __shfl_xor(psum, 4, 64);
            psum += __shfl_xor(psum, 8, 64);
            l_i[i] = l_i[i] * alpha + psum;
            m_i[i] = mnew;
#pragma unroll
            for (int j = 0; j < 4; j++) o_acc[i][j] *= alpha;
        }
        __syncthreads();   // K reads done before P^T overwrite

        // write P^T into K's buffer: KPst[s_local][r_local]
#pragma unroll
        for (int i = 0; i < 4; i++)
#pragma unroll
            for (int j = 0; j < 4; j++)
                KPst[tx * 4 + j][ty * 4 + i] = sc[i][j];
        __syncthreads();

        // O += P V
#pragma unroll 16
        for (int s = 0; s < 64; s++) {
            float4 p4 = *(const float4*)&KPst[s][ty * 4];
            float4 v4 = *(const float4*)&Vs[s][tx * 4];
            float pa[4] = {p4.x, p4.y, p4.z, p4.w};
            float va[4] = {v4.x, v4.y, v4.z, v4.w};
#pragma unroll
            for (int i = 0; i < 4; i++)
#pragma unroll
                for (int j = 0; j < 4; j++)
                    o_acc[i][j] = fmaf(pa[i], va[j], o_acc[i][j]);
        }
    }

    // epilogue: O / l  -> ctx [B*T, NH*HD]
#pragma unroll
    for (int i = 0; i < 4; i++) {
        float invl = 1.0f / l_i[i];
        float4 o;
        o.x = o_acc[i][0] * invl; o.y = o_acc[i][1] * invl;
        o.z = o_acc[i][2] * invl; o.w = o_acc[i][3] * invl;
        size_t base = ((size_t)(b * SEQ + qt * 64 + ty * 4 + i)) * HIDDEN + h * HDIM + tx * 4;
        *(float4*)(ctx + base) = o;
    }
}

// ---------------------------------------------------------------------------
extern "C" void kernel_launch(void* const* d_in, const int* in_sizes, int n_in,
                              void* d_out, int out_size, void* d_ws, size_t ws_size,
                              hipStream_t stream) {
    (void)in_sizes; (void)n_in; (void)out_size; (void)ws_size;
    const float* emb = (const float*)d_in[0];
    const float* Wq  = (const float*)d_in[1];
    const float* Wk  = (const float*)d_in[2];
    const float* Wv  = (const float*)d_in[3];
    const float* Wo  = (const float*)d_in[4];
    const float* W1  = (const float*)d_in[5];
    const float* b1  = (const float*)d_in[6];
    const float* W2  = (const float*)d_in[7];
    const float* b2  = (const float*)d_in[8];
    const float* g1  = (const float*)d_in[9];
    const float* be1 = (const float*)d_in[10];
    const float* g2  = (const float*)d_in[11];
    const float* be2 = (const float*)d_in[12];
    float* out = (float*)d_out;
    float* ws  = (float*)d_ws;

    const size_t U = (size_t)2 * SEQ * HIDDEN;   // 4,194,304 elems (16 MB)
    // ws layout (5*U floats = 84 MB):
    //   ff1 = ws[0 .. 4U)  — overlays h/q/k/v/ctx which are all dead by then
    float* ff1 = ws;
    float* h   = ws;            // LN1 out          (dead after QKV)
    float* q   = ws + U;        //                   (dead after attn)
    float* kb  = ws + 2 * U;
    float* vb  = ws + 3 * U;
    float* ctx = ws;            // overlays h       (dead after Wo gemm)
    float* h2  = ws + 4 * U;    // LN2 out
    // x1 (post-attn residual stream) lives in d_out.

    const int ROWS = 2 * SEQ;   // 4096

    ln_kernel<<<ROWS, 256, 0, stream>>>(emb, g1, be1, h);

    dim3 gProj(HIDDEN / 128, ROWS / 128);         // (8,32) = 256 blocks
    gemm_qkv_kernel<<<dim3(HIDDEN / 128, ROWS / 128, 3), 256, 0, stream>>>(
        h, Wq, Wk, Wv, q, kb, vb);

    attn_kernel<<<dim3(2 * NHEAD, SEQ / 64), 256, 0, stream>>>(q, kb, vb, ctx);

    // x1 = emb + ctx @ Wo   -> d_out
    gemm_kernel<false, false, true><<<gProj, 256, 0, stream>>>(
        ctx, Wo, nullptr, emb, out, ROWS, HIDDEN, HIDDEN);

    ln_kernel<<<ROWS, 256, 0, stream>>>(out, g2, be2, h2);

    // ff1 = relu(h2 @ W1 + b1)
    dim3 gFF(4 * HIDDEN / 128, ROWS / 128);       // (32,32) = 1024 blocks
    gemm_kernel<true, true, false><<<gFF, 256, 0, stream>>>(
        h2, W1, b1, nullptr, ff1, ROWS, 4 * HIDDEN, HIDDEN);

    // out = x1 + ff1 @ W2 + b2   (in-place residual: each element read-then-
    // written by the same thread, no cross-thread aliasing)
    gemm_kernel<true, false, true><<<gProj, 256, 0, stream>>>(
        ff1, W2, b2, out, out, ROWS, HIDDEN, 4 * HIDDEN);
}

// Round 2
// 718.925 us; speedup vs baseline: 2.6711x; 2.6711x over previous
//
#include <hip/hip_runtime.h>
#include <math.h>

#define HIDDEN 1024
#define SEQ    2048
#define NHEAD  16
#define HDIM   64
#define ROWS   (2 * SEQ)

typedef float  floatx4 __attribute__((ext_vector_type(4)));
typedef __bf16 bf16x8  __attribute__((ext_vector_type(8)));
typedef __bf16 bf16x4  __attribute__((ext_vector_type(4)));

#define AS1(p) ((const __attribute__((address_space(1))) void*)(p))
#define AS3(p) ((__attribute__((address_space(3))) void*)(p))

// ---------------------------------------------------------------------------
// LayerNorm: fp32 in -> bf16 out. One block per row, 256 threads x 4 elems.
// ---------------------------------------------------------------------------
__global__ __launch_bounds__(256) void ln_kernel(const float* __restrict__ x,
                                                 const float* __restrict__ g,
                                                 const float* __restrict__ beta,
                                                 __bf16* __restrict__ out) {
    int row = blockIdx.x;
    int tid = threadIdx.x;
    const float* xr = x + (size_t)row * HIDDEN;
    float4 v = *(const float4*)(xr + tid * 4);
    float s  = v.x + v.y + v.z + v.w;
    float s2 = v.x * v.x + v.y * v.y + v.z * v.z + v.w * v.w;
#pragma unroll
    for (int off = 1; off < 64; off <<= 1) {
        s  += __shfl_xor(s, off, 64);
        s2 += __shfl_xor(s2, off, 64);
    }
    __shared__ float red[8];
    int wid = tid >> 6;
    if ((tid & 63) == 0) { red[wid] = s; red[wid + 4] = s2; }
    __syncthreads();
    s  = red[0] + red[1] + red[2] + red[3];
    s2 = red[4] + red[5] + red[6] + red[7];
    float mu  = s * (1.0f / HIDDEN);
    float var = fmaxf(s2 * (1.0f / HIDDEN) - mu * mu, 0.0f);
    float inv = rsqrtf(var + 1e-5f);
    float4 gv = *(const float4*)(g + tid * 4);
    float4 bv = *(const float4*)(beta + tid * 4);
    bf16x4 o;
    o[0] = (__bf16)((v.x - mu) * inv * gv.x + bv.x);
    o[1] = (__bf16)((v.y - mu) * inv * gv.y + bv.y);
    o[2] = (__bf16)((v.z - mu) * inv * gv.z + bv.z);
    o[3] = (__bf16)((v.w - mu) * inv * gv.w + bv.w);
    *(bf16x4*)(out + (size_t)row * HIDDEN + tid * 4) = o;
}

// ---------------------------------------------------------------------------
// Convert + transpose: in fp32 [K][N] -> out bf16 [N][K]. 32x32 LDS tiles.
// ---------------------------------------------------------------------------
__global__ __launch_bounds__(256) void convt_kernel(const float* __restrict__ in,
                                                    __bf16* __restrict__ out,
                                                    int K, int N) {
    __shared__ float t[32][33];
    int n0 = blockIdx.x * 32, k0 = blockIdx.y * 32;
    int r  = threadIdx.x >> 3;
    int c4 = (threadIdx.x & 7) * 4;
    float4 v = *(const float4*)(in + (size_t)(k0 + r) * N + n0 + c4);
    t[r][c4 + 0] = v.x; t[r][c4 + 1] = v.y; t[r][c4 + 2] = v.z; t[r][c4 + 3] = v.w;
    __syncthreads();
    bf16x4 o;
    o[0] = (__bf16)t[c4 + 0][r];
    o[1] = (__bf16)t[c4 + 1][r];
    o[2] = (__bf16)t[c4 + 2][r];
    o[3] = (__bf16)t[c4 + 3][r];
    *(bf16x4*)(out + (size_t)(n0 + r) * K + k0 + c4) = o;
}

// ---------------------------------------------------------------------------
// bf16 MFMA GEMM (m97 structure): C[M,N] = A[M,K] * Bt[N,K]^T
// 128x128 block tile, 4 waves each 64x64 (4x4 tiles of 16x16x32 MFMA),
// BK=32, global_load_lds width-16 staging, 2-barrier K-loop.
// ---------------------------------------------------------------------------
template <typename OutT, bool BIAS, bool RELU, bool RES>
__global__ __launch_bounds__(256) void mgemm(const __bf16* __restrict__ A,
                                             const __bf16* __restrict__ Bt,
                                             const float* __restrict__ bias,
                                             const float* __restrict__ res,
                                             OutT* __restrict__ C,
                                             int M, int N, int K) {
    __shared__ __bf16 As[128 * 32];
    __shared__ __bf16 Bs[128 * 32];
    int tid  = threadIdx.x;
    int lane = tid & 63;
    int wave = tid >> 6;
    int m0 = blockIdx.y * 128, n0 = blockIdx.x * 128;
    int wr = wave >> 1, wc = wave & 1;

    floatx4 acc[4][4] = {};

    // staging: per K-step, A tile 128x32 bf16 = 8KB = 8 chunks of 1KB.
    // wave w loads chunks {w, w+4}; lane l -> row 16c + (l>>2), kseg (l&3)*8.
    int sr = lane >> 2;
    int sk = (lane & 3) * 8;
    const __bf16* ga0 = A  + (size_t)(m0 + wave * 16 + sr) * K + sk;
    const __bf16* ga1 = ga0 + (size_t)64 * K;
    const __bf16* gb0 = Bt + (size_t)(n0 + wave * 16 + sr) * K + sk;
    const __bf16* gb1 = gb0 + (size_t)64 * K;
    __bf16* la0 = &As[wave * 512];
    __bf16* la1 = &As[2048 + wave * 512];
    __bf16* lb0 = &Bs[wave * 512];
    __bf16* lb1 = &Bs[2048 + wave * 512];

    int fm = lane & 15;            // m / n within 16x16 tile
    int fk = (lane >> 4) * 8;      // k-segment

    for (int k0 = 0; k0 < K; k0 += 32) {
        __builtin_amdgcn_global_load_lds(AS1(ga0 + k0), AS3(la0), 16, 0, 0);
        __builtin_amdgcn_global_load_lds(AS1(ga1 + k0), AS3(la1), 16, 0, 0);
        __builtin_amdgcn_global_load_lds(AS1(gb0 + k0), AS3(lb0), 16, 0, 0);
        __builtin_amdgcn_global_load_lds(AS1(gb1 + k0), AS3(lb1), 16, 0, 0);
        __syncthreads();

        bf16x8 af[4], bfv[4];
#pragma unroll
        for (int i = 0; i < 4; i++)
            af[i] = *(const bf16x8*)(As + (size_t)(wr * 64 + i * 16 + fm) * 32 + fk);
#pragma unroll
        for (int j = 0; j < 4; j++)
            bfv[j] = *(const bf16x8*)(Bs + (size_t)(wc * 64 + j * 16 + fm) * 32 + fk);
#pragma unroll
        for (int i = 0; i < 4; i++)
#pragma unroll
            for (int j = 0; j < 4; j++)
                acc[i][j] = __builtin_amdgcn_mfma_f32_16x16x32_bf16(
                    af[i], bfv[j], acc[i][j], 0, 0, 0);
        __syncthreads();
    }

    // epilogue: C/D layout col = lane&15, row = (lane>>4)*4 + r
#pragma unroll
    for (int i = 0; i < 4; i++) {
#pragma unroll
        for (int j = 0; j < 4; j++) {
            int row = m0 + wr * 64 + i * 16 + (lane >> 4) * 4;
            int col = n0 + wc * 64 + j * 16 + (lane & 15);
#pragma unroll
            for (int r = 0; r < 4; r++) {
                float v = acc[i][j][r];
                if (BIAS) v += bias[col];
                if (RELU) v = fmaxf(v, 0.0f);
                if (RES)  v += res[(size_t)(row + r) * N + col];
                C[(size_t)(row + r) * N + col] = (OutT)v;
            }
        }
    }
}

// ---------------------------------------------------------------------------
// Flash-style causal attention, fp32 compute, bf16 qkv in / bf16 ctx out.
// qkv layout: [B*T, 3*HIDDEN] with q|k|v concatenated along the column dim.
// ---------------------------------------------------------------------------
__global__ __launch_bounds__(256) void attn_kernel(const __bf16* __restrict__ qkv,
                                                   __bf16* __restrict__ ctx) {
    __shared__ float Qst[64][68];    // [d][r]
    __shared__ float KPst[64][68];   // K phase: [d][s];  P phase: [s][r]
    __shared__ float Vs[64][68];     // [s][d]
    const int QKVW = 3 * HIDDEN;

    int bh = blockIdx.x;             // 0..31
    int qt = blockIdx.y;             // 0..31
    int b = bh >> 4, h = bh & 15;
    int tid = threadIdx.x;
    int tx = tid & 15, ty = tid >> 4;

    const __bf16* Qp = qkv + (size_t)(b * SEQ + qt * 64) * QKVW + h * HDIM;
    {
        int r = tid >> 2;
        int dseg = (tid & 3) * 16;
        bf16x8 a = *(const bf16x8*)(Qp + (size_t)r * QKVW + dseg);
        bf16x8 c = *(const bf16x8*)(Qp + (size_t)r * QKVW + dseg + 8);
#pragma unroll
        for (int i = 0; i < 8; i++) {
            Qst[dseg + i][r]     = (float)a[i];
            Qst[dseg + 8 + i][r] = (float)c[i];
        }
    }

    float m_i[4], l_i[4], o_acc[4][4];
#pragma unroll
    for (int i = 0; i < 4; i++) {
        m_i[i] = -INFINITY; l_i[i] = 0.0f;
#pragma unroll
        for (int j = 0; j < 4; j++) o_acc[i][j] = 0.0f;
    }
    int qrow0 = qt * 64;

    for (int kt = 0; kt <= qt; kt++) {
        __syncthreads();   // prev-iter LDS reads done (also covers Q stores)
        {
            const __bf16* Kp = qkv + (size_t)(b * SEQ + kt * 64) * QKVW + HIDDEN + h * HDIM;
            const __bf16* Vp = Kp + HIDDEN;
            int s = tid >> 2;
            int dseg = (tid & 3) * 16;
            bf16x8 k0v = *(const bf16x8*)(Kp + (size_t)s * QKVW + dseg);
            bf16x8 k1v = *(const bf16x8*)(Kp + (size_t)s * QKVW + dseg + 8);
            bf16x8 v0v = *(const bf16x8*)(Vp + (size_t)s * QKVW + dseg);
            bf16x8 v1v = *(const bf16x8*)(Vp + (size_t)s * QKVW + dseg + 8);
#pragma unroll
            for (int i = 0; i < 8; i++) {
                KPst[dseg + i][s]     = (float)k0v[i];
                KPst[dseg + 8 + i][s] = (float)k1v[i];
                Vs[s][dseg + i]       = (float)v0v[i];
                Vs[s][dseg + 8 + i]   = (float)v1v[i];
            }
        }
        __syncthreads();

        // scores S = Q K^T   (4x4 per thread)
        float sc[4][4];
#pragma unroll
        for (int i = 0; i < 4; i++)
#pragma unroll
            for (int j = 0; j < 4; j++) sc[i][j] = 0.0f;
#pragma unroll 16
        for (int d = 0; d < 64; d++) {
            float4 q4 = *(const float4*)&Qst[d][ty * 4];
            float4 k4 = *(const float4*)&KPst[d][tx * 4];
            float qa[4] = {q4.x, q4.y, q4.z, q4.w};
            float ka[4] = {k4.x, k4.y, k4.z, k4.w};
#pragma unroll
            for (int i = 0; i < 4; i++)
#pragma unroll
                for (int j = 0; j < 4; j++)
                    sc[i][j] = fmaf(qa[i], ka[j], sc[i][j]);
        }

        // online softmax (rows reduce across the 16 tx lanes)
#pragma unroll
        for (int i = 0; i < 4; i++) {
            int r = qrow0 + ty * 4 + i;
            float rmax = -INFINITY;
#pragma unroll
            for (int j = 0; j < 4; j++) {
                int s = kt * 64 + tx * 4 + j;
                sc[i][j] = (s <= r) ? sc[i][j] * 0.125f : -INFINITY;
                rmax = fmaxf(rmax, sc[i][j]);
            }
            rmax = fmaxf(rmax, __shfl_xor(rmax, 1, 64));
            rmax = fmaxf(rmax, __shfl_xor(rmax, 2, 64));
            rmax = fmaxf(rmax, __shfl_xor(rmax, 4, 64));
            rmax = fmaxf(rmax, __shfl_xor(rmax, 8, 64));
            float mnew = fmaxf(m_i[i], rmax);
            float alpha = __expf(m_i[i] - mnew);
            float psum = 0.0f;
#pragma unroll
            for (int j = 0; j < 4; j++) {
                sc[i][j] = __expf(sc[i][j] - mnew);
                psum += sc[i][j];
            }
            psum += __shfl_xor(psum, 1, 64);
            psum += __shfl_xor(psum, 2, 64);
            psum += __shfl_xor(psum, 4, 64);
            psum += __shfl_xor(psum, 8, 64);
            l_i[i] = l_i[i] * alpha + psum;
            m_i[i] = mnew;
#pragma unroll
            for (int j = 0; j < 4; j++) o_acc[i][j] *= alpha;
        }
        __syncthreads();   // K reads done before P^T overwrite

#pragma unroll
        for (int i = 0; i < 4; i++)
#pragma unroll
            for (int j = 0; j < 4; j++)
                KPst[tx * 4 + j][ty * 4 + i] = sc[i][j];
        __syncthreads();

        // O += P V
#pragma unroll 16
        for (int s = 0; s < 64; s++) {
            float4 p4 = *(const float4*)&KPst[s][ty * 4];
            float4 v4 = *(const float4*)&Vs[s][tx * 4];
            float pa[4] = {p4.x, p4.y, p4.z, p4.w};
            float va[4] = {v4.x, v4.y, v4.z, v4.w};
#pragma unroll
            for (int i = 0; i < 4; i++)
#pragma unroll
                for (int j = 0; j < 4; j++)
                    o_acc[i][j] = fmaf(pa[i], va[j], o_acc[i][j]);
        }
    }

    // epilogue: O / l  -> ctx [B*T, HIDDEN] bf16
#pragma unroll
    for (int i = 0; i < 4; i++) {
        float invl = 1.0f / l_i[i];
        bf16x4 o;
        o[0] = (__bf16)(o_acc[i][0] * invl);
        o[1] = (__bf16)(o_acc[i][1] * invl);
        o[2] = (__bf16)(o_acc[i][2] * invl);
        o[3] = (__bf16)(o_acc[i][3] * invl);
        size_t base = ((size_t)(b * SEQ + qt * 64 + ty * 4 + i)) * HIDDEN + h * HDIM + tx * 4;
        *(bf16x4*)(ctx + base) = o;
    }
}

// ---------------------------------------------------------------------------
extern "C" void kernel_launch(void* const* d_in, const int* in_sizes, int n_in,
                              void* d_out, int out_size, void* d_ws, size_t ws_size,
                              hipStream_t stream) {
    (void)in_sizes; (void)n_in; (void)out_size; (void)ws_size;
    const float* emb = (const float*)d_in[0];
    const float* Wq  = (const float*)d_in[1];
    const float* Wk  = (const float*)d_in[2];
    const float* Wv  = (const float*)d_in[3];
    const float* Wo  = (const float*)d_in[4];
    const float* W1  = (const float*)d_in[5];
    const float* b1  = (const float*)d_in[6];
    const float* W2  = (const float*)d_in[7];
    const float* b2  = (const float*)d_in[8];
    const float* g1  = (const float*)d_in[9];
    const float* be1 = (const float*)d_in[10];
    const float* g2  = (const float*)d_in[11];
    const float* be2 = (const float*)d_in[12];
    float* out = (float*)d_out;

    // ws layout (bf16 elems; 1M elems = 2MB). Total 32M elems = 64 MB.
    //   [0,4M)   h        (dead after QKV gemm)  -> reused as ctx
    //   [4,16M)  qkv      (dead after attention)
    //   [0,16M)  ff1      (overlays h/ctx + qkv, alive after LN2)
    //   [16,20M) h2
    //   [20,23M) BtQKV  [23,24M) BtO  [24,28M) Bt1  [28,32M) Bt2
    __bf16* wsb = (__bf16*)d_ws;
    const size_t ME = 1024 * 1024;
    __bf16* h     = wsb;
    __bf16* qkv   = wsb + 4 * ME;
    __bf16* ctx   = wsb;
    __bf16* ff1   = wsb;
    __bf16* h2    = wsb + 16 * ME;
    __bf16* BtQKV = wsb + 20 * ME;
    __bf16* BtO   = wsb + 23 * ME;
    __bf16* Bt1   = wsb + 24 * ME;
    __bf16* Bt2   = wsb + 28 * ME;

    // weight convert + transpose to [N][K] bf16
    convt_kernel<<<dim3(32, 32),  256, 0, stream>>>(Wq, BtQKV,            1024, 1024);
    convt_kernel<<<dim3(32, 32),  256, 0, stream>>>(Wk, BtQKV + 1024*1024, 1024, 1024);
    convt_kernel<<<dim3(32, 32),  256, 0, stream>>>(Wv, BtQKV + 2*1024*1024, 1024, 1024);
    convt_kernel<<<dim3(32, 32),  256, 0, stream>>>(Wo, BtO,              1024, 1024);
    convt_kernel<<<dim3(128, 32), 256, 0, stream>>>(W1, Bt1,              1024, 4096);
    convt_kernel<<<dim3(32, 128), 256, 0, stream>>>(W2, Bt2,              4096, 1024);

    ln_kernel<<<ROWS, 256, 0, stream>>>(emb, g1, be1, h);

    // qkv = h @ [Wq|Wk|Wv]
    mgemm<__bf16, false, false, false><<<dim3(24, 32), 256, 0, stream>>>(
        h, BtQKV, nullptr, nullptr, qkv, ROWS, 3072, 1024);

    attn_kernel<<<dim3(2 * NHEAD, SEQ / 64), 256, 0, stream>>>(qkv, ctx);

    // x1 = emb + ctx @ Wo  -> d_out (fp32)
    mgemm<float, false, false, true><<<dim3(8, 32), 256, 0, stream>>>(
        ctx, BtO, nullptr, emb, out, ROWS, 1024, 1024);

    ln_kernel<<<ROWS, 256, 0, stream>>>(out, g2, be2, h2);

    // ff1 = relu(h2 @ W1 + b1) (bf16)
    mgemm<__bf16, true, true, false><<<dim3(32, 32), 256, 0, stream>>>(
        h2, Bt1, b1, nullptr, ff1, ROWS, 4096, 1024);

    // out = x1 + ff1 @ W2 + b2 (in-place residual, same-thread RMW)
    mgemm<float, true, false, true><<<dim3(8, 32), 256, 0, stream>>>(
        ff1, Bt2, b2, out, out, ROWS, 1024, 4096);
}

// Round 3
// 417.169 us; speedup vs baseline: 4.6032x; 1.7233x over previous
//
#include <hip/hip_runtime.h>
#include <math.h>

#define HIDDEN 1024
#define SEQ    2048
#define NHEAD  16
#define HDIM   64
#define ROWS   (2 * SEQ)

typedef float  floatx4 __attribute__((ext_vector_type(4)));
typedef __bf16 bf16x8  __attribute__((ext_vector_type(8)));
typedef __bf16 bf16x4  __attribute__((ext_vector_type(4)));

#define AS1(p) ((const __attribute__((address_space(1))) void*)(p))
#define AS3(p) ((__attribute__((address_space(3))) void*)(p))

// swizzled byte-chunk offset (in elements): 16B chunks XOR'd by row&7
#define SWZ(row, chunk) ((((chunk) ^ ((row) & 7)) * 8))

// ---------------------------------------------------------------------------
// LayerNorm: fp32 in -> bf16 out. One block per row, 256 threads x 4 elems.
// ---------------------------------------------------------------------------
__global__ __launch_bounds__(256) void ln_kernel(const float* __restrict__ x,
                                                 const float* __restrict__ g,
                                                 const float* __restrict__ beta,
                                                 __bf16* __restrict__ out) {
    int row = blockIdx.x;
    int tid = threadIdx.x;
    const float* xr = x + (size_t)row * HIDDEN;
    float4 v = *(const float4*)(xr + tid * 4);
    float s  = v.x + v.y + v.z + v.w;
    float s2 = v.x * v.x + v.y * v.y + v.z * v.z + v.w * v.w;
#pragma unroll
    for (int off = 1; off < 64; off <<= 1) {
        s  += __shfl_xor(s, off, 64);
        s2 += __shfl_xor(s2, off, 64);
    }
    __shared__ float red[8];
    int wid = tid >> 6;
    if ((tid & 63) == 0) { red[wid] = s; red[wid + 4] = s2; }
    __syncthreads();
    s  = red[0] + red[1] + red[2] + red[3];
    s2 = red[4] + red[5] + red[6] + red[7];
    float mu  = s * (1.0f / HIDDEN);
    float var = fmaxf(s2 * (1.0f / HIDDEN) - mu * mu, 0.0f);
    float inv = rsqrtf(var + 1e-5f);
    float4 gv = *(const float4*)(g + tid * 4);
    float4 bv = *(const float4*)(beta + tid * 4);
    bf16x4 o;
    o[0] = (__bf16)((v.x - mu) * inv * gv.x + bv.x);
    o[1] = (__bf16)((v.y - mu) * inv * gv.y + bv.y);
    o[2] = (__bf16)((v.z - mu) * inv * gv.z + bv.z);
    o[3] = (__bf16)((v.w - mu) * inv * gv.w + bv.w);
    *(bf16x4*)(out + (size_t)row * HIDDEN + tid * 4) = o;
}

// ---------------------------------------------------------------------------
// Convert + transpose: in fp32 [K][N] -> out bf16 [N][K]. 32x32 LDS tiles.
// ---------------------------------------------------------------------------
__global__ __launch_bounds__(256) void convt_kernel(const float* __restrict__ in,
                                                    __bf16* __restrict__ out,
                                                    int K, int N) {
    __shared__ float t[32][33];
    int n0 = blockIdx.x * 32, k0 = blockIdx.y * 32;
    int r  = threadIdx.x >> 3;
    int c4 = (threadIdx.x & 7) * 4;
    float4 v = *(const float4*)(in + (size_t)(k0 + r) * N + n0 + c4);
    t[r][c4 + 0] = v.x; t[r][c4 + 1] = v.y; t[r][c4 + 2] = v.z; t[r][c4 + 3] = v.w;
    __syncthreads();
    bf16x4 o;
    o[0] = (__bf16)t[c4 + 0][r];
    o[1] = (__bf16)t[c4 + 1][r];
    o[2] = (__bf16)t[c4 + 2][r];
    o[3] = (__bf16)t[c4 + 3][r];
    *(bf16x4*)(out + (size_t)(n0 + r) * K + k0 + c4) = o;
}

// ---------------------------------------------------------------------------
// bf16 MFMA GEMM (m97 structure): C[M,N] = A[M,K] * Bt[N,K]^T
// ---------------------------------------------------------------------------
template <typename OutT, bool BIAS, bool RELU, bool RES>
__global__ __launch_bounds__(256) void mgemm(const __bf16* __restrict__ A,
                                             const __bf16* __restrict__ Bt,
                                             const float* __restrict__ bias,
                                             const float* __restrict__ res,
                                             OutT* __restrict__ C,
                                             int M, int N, int K) {
    __shared__ __bf16 As[128 * 32];
    __shared__ __bf16 Bs[128 * 32];
    int tid  = threadIdx.x;
    int lane = tid & 63;
    int wave = tid >> 6;
    int m0 = blockIdx.y * 128, n0 = blockIdx.x * 128;
    int wr = wave >> 1, wc = wave & 1;

    floatx4 acc[4][4] = {};

    int sr = lane >> 2;
    int sk = (lane & 3) * 8;
    const __bf16* ga0 = A  + (size_t)(m0 + wave * 16 + sr) * K + sk;
    const __bf16* ga1 = ga0 + (size_t)64 * K;
    const __bf16* gb0 = Bt + (size_t)(n0 + wave * 16 + sr) * K + sk;
    const __bf16* gb1 = gb0 + (size_t)64 * K;
    __bf16* la0 = &As[wave * 512];
    __bf16* la1 = &As[2048 + wave * 512];
    __bf16* lb0 = &Bs[wave * 512];
    __bf16* lb1 = &Bs[2048 + wave * 512];

    int fm = lane & 15;
    int fk = (lane >> 4) * 8;

    for (int k0 = 0; k0 < K; k0 += 32) {
        __builtin_amdgcn_global_load_lds(AS1(ga0 + k0), AS3(la0), 16, 0, 0);
        __builtin_amdgcn_global_load_lds(AS1(ga1 + k0), AS3(la1), 16, 0, 0);
        __builtin_amdgcn_global_load_lds(AS1(gb0 + k0), AS3(lb0), 16, 0, 0);
        __builtin_amdgcn_global_load_lds(AS1(gb1 + k0), AS3(lb1), 16, 0, 0);
        __syncthreads();

        bf16x8 af[4], bfv[4];
#pragma unroll
        for (int i = 0; i < 4; i++)
            af[i] = *(const bf16x8*)(As + (size_t)(wr * 64 + i * 16 + fm) * 32 + fk);
#pragma unroll
        for (int j = 0; j < 4; j++)
            bfv[j] = *(const bf16x8*)(Bs + (size_t)(wc * 64 + j * 16 + fm) * 32 + fk);
#pragma unroll
        for (int i = 0; i < 4; i++)
#pragma unroll
            for (int j = 0; j < 4; j++)
                acc[i][j] = __builtin_amdgcn_mfma_f32_16x16x32_bf16(
                    af[i], bfv[j], acc[i][j], 0, 0, 0);
        __syncthreads();
    }

#pragma unroll
    for (int i = 0; i < 4; i++) {
#pragma unroll
        for (int j = 0; j < 4; j++) {
            int row = m0 + wr * 64 + i * 16 + (lane >> 4) * 4;
            int col = n0 + wc * 64 + j * 16 + (lane & 15);
#pragma unroll
            for (int r = 0; r < 4; r++) {
                float v = acc[i][j][r];
                if (BIAS) v += bias[col];
                if (RELU) v = fmaxf(v, 0.0f);
                if (RES)  v += res[(size_t)(row + r) * N + col];
                C[(size_t)(row + r) * N + col] = (OutT)v;
            }
        }
    }
}

// ---------------------------------------------------------------------------
// V transpose: qkv v-part [B*T][3H] -> Vt[bh][d][T]   (64x64 LDS tiles)
// ---------------------------------------------------------------------------
__global__ __launch_bounds__(256) void vtrans(const __bf16* __restrict__ qkv,
                                              __bf16* __restrict__ Vt) {
    __shared__ __bf16 t[64 * 64];    // swizzled [d][t]
    int bh = blockIdx.x, b = bh >> 4, h = bh & 15;
    int t0 = blockIdx.y * 64;
    int tid = threadIdx.x;
    int lt = tid >> 2;             // local t
    int ds = (tid & 3) * 16;       // d segment
    const __bf16* vp = qkv + (size_t)(b * SEQ + t0 + lt) * (3 * HIDDEN)
                     + 2 * HIDDEN + h * HDIM + ds;
    bf16x8 a = *(const bf16x8*)vp;
    bf16x8 c = *(const bf16x8*)(vp + 8);
#pragma unroll
    for (int i = 0; i < 8; i++) {
        int d0 = ds + i, d1 = ds + 8 + i;
        t[d0 * 64 + SWZ(d0, lt >> 3) + (lt & 7)] = a[i];
        t[d1 * 64 + SWZ(d1, lt >> 3) + (lt & 7)] = c[i];
    }
    __syncthreads();
    int dr = tid >> 2;             // d row
    int c2 = (tid & 3) * 2;        // chunk pair
    bf16x8 o0 = *(const bf16x8*)&t[dr * 64 + SWZ(dr, c2)];
    bf16x8 o1 = *(const bf16x8*)&t[dr * 64 + SWZ(dr, c2 + 1)];
    __bf16* op = Vt + ((size_t)bh * HDIM + dr) * SEQ + t0;
    *(bf16x8*)(op + c2 * 8)     = o0;
    *(bf16x8*)(op + c2 * 8 + 8) = o1;
}

// ---------------------------------------------------------------------------
// MFMA flash attention. 1 block per (bh, q-tile 64). 4 waves x 16 q-rows.
// K,V^T tiles staged in LDS (XOR-swizzled 16B chunks); P round-trips through
// per-wave-private LDS for the C-layout -> A-layout transform.
// ---------------------------------------------------------------------------
__global__ __launch_bounds__(256) void attn_mfma(const __bf16* __restrict__ qkv,
                                                 const __bf16* __restrict__ Vt,
                                                 __bf16* __restrict__ ctx) {
    __shared__ __bf16 Ks[64 * 64];
    __shared__ __bf16 Vs[64 * 64];
    __shared__ __bf16 Ps[4][16 * 64];
    const int QKVW = 3 * HIDDEN;

    int bh = blockIdx.x;
    int qt = gridDim.y - 1 - blockIdx.y;   // heavy q-tiles dispatch first
    int b = bh >> 4, h = bh & 15;
    int tid = threadIdx.x;
    int lane = tid & 63;
    int w = tid >> 6;
    int m = lane & 15;       // fragment m/n index
    int g = lane >> 4;       // fragment k-group

    // Q fragments (A-operand) straight from global, pre-scaled by 1/8 (exact)
    bf16x8 qf[2];
    {
        const __bf16* Qp = qkv + (size_t)(b * SEQ + qt * 64 + w * 16 + m) * QKVW
                         + h * HDIM + g * 8;
        qf[0] = *(const bf16x8*)(Qp);
        qf[1] = *(const bf16x8*)(Qp + 32);
#pragma unroll
        for (int t = 0; t < 2; t++)
#pragma unroll
            for (int i = 0; i < 8; i++)
                qf[t][i] = (__bf16)((float)qf[t][i] * 0.125f);
    }

    floatx4 oacc[4] = {};
    float m_i[4], l_i[4];
#pragma unroll
    for (int r = 0; r < 4; r++) { m_i[r] = -INFINITY; l_i[r] = 0.0f; }

    int srow = tid >> 2;           // staging row 0..63
    int sc0  = (tid & 3) * 2;      // staging chunk pair
    const __bf16* Kg = qkv + (size_t)(b * SEQ) * QKVW + HIDDEN + h * HDIM;
    const __bf16* Vg = Vt + (size_t)bh * HDIM * SEQ;

    for (int kt = 0; kt <= qt; kt++) {
        __syncthreads();
        {
            const __bf16* kp = Kg + (size_t)(kt * 64 + srow) * QKVW + sc0 * 8;
            bf16x8 k0 = *(const bf16x8*)kp;
            bf16x8 k1 = *(const bf16x8*)(kp + 8);
            const __bf16* vp = Vg + (size_t)srow * SEQ + kt * 64 + sc0 * 8;
            bf16x8 v0 = *(const bf16x8*)vp;
            bf16x8 v1 = *(const bf16x8*)(vp + 8);
            *(bf16x8*)&Ks[srow * 64 + SWZ(srow, sc0)]     = k0;
            *(bf16x8*)&Ks[srow * 64 + SWZ(srow, sc0 + 1)] = k1;
            *(bf16x8*)&Vs[srow * 64 + SWZ(srow, sc0)]     = v0;
            *(bf16x8*)&Vs[srow * 64 + SWZ(srow, sc0 + 1)] = v1;
        }
        __syncthreads();

        // S = (Q/8) K^T : 4 key-subtiles x 2 k-chunks
        floatx4 sacc[4] = {};
#pragma unroll
        for (int j = 0; j < 4; j++) {
#pragma unroll
            for (int t = 0; t < 2; t++) {
                int kr = 16 * j + m;
                bf16x8 kf = *(const bf16x8*)&Ks[kr * 64 + SWZ(kr, g + 4 * t)];
                sacc[j] = __builtin_amdgcn_mfma_f32_16x16x32_bf16(
                    qf[t], kf, sacc[j], 0, 0, 0);
            }
        }

        // causal mask: only the diagonal k-tile needs it (wave-uniform branch)
        if (kt == qt) {
            int qlocal = w * 16 + 4 * g;
#pragma unroll
            for (int j = 0; j < 4; j++)
#pragma unroll
                for (int r = 0; r < 4; r++)
                    if (16 * j + m > qlocal + r) sacc[j][r] = -INFINITY;
        }

        // online softmax (rows live in lanes with common lane>>4)
        float alpha[4];
#pragma unroll
        for (int r = 0; r < 4; r++) {
            float mx = fmaxf(fmaxf(sacc[0][r], sacc[1][r]),
                             fmaxf(sacc[2][r], sacc[3][r]));
            mx = fmaxf(mx, __shfl_xor(mx, 1, 64));
            mx = fmaxf(mx, __shfl_xor(mx, 2, 64));
            mx = fmaxf(mx, __shfl_xor(mx, 4, 64));
            mx = fmaxf(mx, __shfl_xor(mx, 8, 64));
            float mnew = fmaxf(m_i[r], mx);
            alpha[r] = __expf(m_i[r] - mnew);
            float ps = 0.0f;
#pragma unroll
            for (int j = 0; j < 4; j++) {
                float p = __expf(sacc[j][r] - mnew);
                sacc[j][r] = p;
                ps += p;
            }
            ps += __shfl_xor(ps, 1, 64);
            ps += __shfl_xor(ps, 2, 64);
            ps += __shfl_xor(ps, 4, 64);
            ps += __shfl_xor(ps, 8, 64);
            l_i[r] = l_i[r] * alpha[r] + ps;
            m_i[r] = mnew;
        }
#pragma unroll
        for (int jd = 0; jd < 4; jd++)
#pragma unroll
            for (int r = 0; r < 4; r++) oacc[jd][r] *= alpha[r];

        // P: C-layout regs -> per-wave-private LDS (A-layout), bf16
        __bf16* Pw = &Ps[w][0];
#pragma unroll
        for (int j = 0; j < 4; j++)
#pragma unroll
            for (int r = 0; r < 4; r++) {
                int row = 4 * g + r;
                int key = 16 * j + m;
                Pw[row * 64 + SWZ(row, key >> 3) + (key & 7)] = (__bf16)sacc[j][r];
            }

        // O += P V  (A-frag from Pw, B-frag from Vs = V^T)
#pragma unroll
        for (int t = 0; t < 2; t++) {
            bf16x8 pf = *(const bf16x8*)&Pw[m * 64 + SWZ(m, g + 4 * t)];
#pragma unroll
            for (int jd = 0; jd < 4; jd++) {
                int vr = 16 * jd + m;
                bf16x8 vf = *(const bf16x8*)&Vs[vr * 64 + SWZ(vr, g + 4 * t)];
                oacc[jd] = __builtin_amdgcn_mfma_f32_16x16x32_bf16(
                    pf, vf, oacc[jd], 0, 0, 0);
            }
        }
    }

    // epilogue: O / l -> ctx [B*T][HID]
#pragma unroll
    for (int r = 0; r < 4; r++) {
        float invl = 1.0f / l_i[r];
        int row = qt * 64 + w * 16 + 4 * g + r;
        __bf16* cp = ctx + (size_t)(b * SEQ + row) * HIDDEN + h * HDIM;
#pragma unroll
        for (int jd = 0; jd < 4; jd++)
            cp[16 * jd + m] = (__bf16)(oacc[jd][r] * invl);
    }
}

// ---------------------------------------------------------------------------
extern "C" void kernel_launch(void* const* d_in, const int* in_sizes, int n_in,
                              void* d_out, int out_size, void* d_ws, size_t ws_size,
                              hipStream_t stream) {
    (void)in_sizes; (void)n_in; (void)out_size; (void)ws_size;
    const float* emb = (const float*)d_in[0];
    const float* Wq  = (const float*)d_in[1];
    const float* Wk  = (const float*)d_in[2];
    const float* Wv  = (const float*)d_in[3];
    const float* Wo  = (const float*)d_in[4];
    const float* W1  = (const float*)d_in[5];
    const float* b1  = (const float*)d_in[6];
    const float* W2  = (const float*)d_in[7];
    const float* b2  = (const float*)d_in[8];
    const float* g1  = (const float*)d_in[9];
    const float* be1 = (const float*)d_in[10];
    const float* g2  = (const float*)d_in[11];
    const float* be2 = (const float*)d_in[12];
    float* out = (float*)d_out;

    // ws layout (bf16 elems; 1M elems = 2MB). Total 36M elems = 72 MB.
    //   [0,4M)   h (LN1 out; dead after QKV) -> reused as ctx
    //   [4,16M)  qkv (dead after attention)
    //   [0,16M)  ff1 (overlays h/ctx + qkv)
    //   [16,20M) h2
    //   [20,23M) BtQKV  [23,24M) BtO  [24,28M) Bt1  [28,32M) Bt2
    //   [32,36M) Vt (per-head V^T)
    __bf16* wsb = (__bf16*)d_ws;
    const size_t ME = 1024 * 1024;
    __bf16* h     = wsb;
    __bf16* qkv   = wsb + 4 * ME;
    __bf16* ctx   = wsb;
    __bf16* ff1   = wsb;
    __bf16* h2    = wsb + 16 * ME;
    __bf16* BtQKV = wsb + 20 * ME;
    __bf16* BtO   = wsb + 23 * ME;
    __bf16* Bt1   = wsb + 24 * ME;
    __bf16* Bt2   = wsb + 28 * ME;
    __bf16* Vt    = wsb + 32 * ME;

    convt_kernel<<<dim3(32, 32),  256, 0, stream>>>(Wq, BtQKV,              1024, 1024);
    convt_kernel<<<dim3(32, 32),  256, 0, stream>>>(Wk, BtQKV + 1024*1024,  1024, 1024);
    convt_kernel<<<dim3(32, 32),  256, 0, stream>>>(Wv, BtQKV + 2*1024*1024,1024, 1024);
    convt_kernel<<<dim3(32, 32),  256, 0, stream>>>(Wo, BtO,                1024, 1024);
    convt_kernel<<<dim3(128, 32), 256, 0, stream>>>(W1, Bt1,                1024, 4096);
    convt_kernel<<<dim3(32, 128), 256, 0, stream>>>(W2, Bt2,                4096, 1024);

    ln_kernel<<<ROWS, 256, 0, stream>>>(emb, g1, be1, h);

    mgemm<__bf16, false, false, false><<<dim3(24, 32), 256, 0, stream>>>(
        h, BtQKV, nullptr, nullptr, qkv, ROWS, 3072, 1024);

    vtrans<<<dim3(32, 32), 256, 0, stream>>>(qkv, Vt);

    attn_mfma<<<dim3(32, 32), 256, 0, stream>>>(qkv, Vt, ctx);

    mgemm<float, false, false, true><<<dim3(8, 32), 256, 0, stream>>>(
        ctx, BtO, nullptr, emb, out, ROWS, 1024, 1024);

    ln_kernel<<<ROWS, 256, 0, stream>>>(out, g2, be2, h2);

    mgemm<__bf16, true, true, false><<<dim3(32, 32), 256, 0, stream>>>(
        h2, Bt1, b1, nullptr, ff1, ROWS, 4096, 1024);

    mgemm<float, true, false, true><<<dim3(8, 32), 256, 0, stream>>>(
        ff1, Bt2, b2, out, out, ROWS, 1024, 4096);
}

// Round 4
// 391.977 us; speedup vs baseline: 4.8991x; 1.0643x over previous
//
#include <hip/hip_runtime.h>
#include <math.h>

#define HIDDEN 1024
#define SEQ    2048
#define NHEAD  16
#define HDIM   64
#define ROWS   (2 * SEQ)

typedef float  floatx4 __attribute__((ext_vector_type(4)));
typedef __bf16 bf16x8  __attribute__((ext_vector_type(8)));
typedef __bf16 bf16x4  __attribute__((ext_vector_type(4)));

#define AS1(p) ((const __attribute__((address_space(1))) void*)(p))
#define AS3(p) ((__attribute__((address_space(3))) void*)(p))

// swizzled byte-chunk offset (in elements): 16B chunks XOR'd by row&7
#define SWZ(row, chunk) ((((chunk) ^ ((row) & 7)) * 8))

// ---------------------------------------------------------------------------
// LayerNorm: fp32 in -> bf16 out. One block per row, 256 threads x 4 elems.
// ---------------------------------------------------------------------------
__global__ __launch_bounds__(256) void ln_kernel(const float* __restrict__ x,
                                                 const float* __restrict__ g,
                                                 const float* __restrict__ beta,
                                                 __bf16* __restrict__ out) {
    int row = blockIdx.x;
    int tid = threadIdx.x;
    const float* xr = x + (size_t)row * HIDDEN;
    float4 v = *(const float4*)(xr + tid * 4);
    float s  = v.x + v.y + v.z + v.w;
    float s2 = v.x * v.x + v.y * v.y + v.z * v.z + v.w * v.w;
#pragma unroll
    for (int off = 1; off < 64; off <<= 1) {
        s  += __shfl_xor(s, off, 64);
        s2 += __shfl_xor(s2, off, 64);
    }
    __shared__ float red[8];
    int wid = tid >> 6;
    if ((tid & 63) == 0) { red[wid] = s; red[wid + 4] = s2; }
    __syncthreads();
    s  = red[0] + red[1] + red[2] + red[3];
    s2 = red[4] + red[5] + red[6] + red[7];
    float mu  = s * (1.0f / HIDDEN);
    float var = fmaxf(s2 * (1.0f / HIDDEN) - mu * mu, 0.0f);
    float inv = rsqrtf(var + 1e-5f);
    float4 gv = *(const float4*)(g + tid * 4);
    float4 bv = *(const float4*)(beta + tid * 4);
    bf16x4 o;
    o[0] = (__bf16)((v.x - mu) * inv * gv.x + bv.x);
    o[1] = (__bf16)((v.y - mu) * inv * gv.y + bv.y);
    o[2] = (__bf16)((v.z - mu) * inv * gv.z + bv.z);
    o[3] = (__bf16)((v.w - mu) * inv * gv.w + bv.w);
    *(bf16x4*)(out + (size_t)row * HIDDEN + tid * 4) = o;
}

// ---------------------------------------------------------------------------
// All weight converts (fp32 [K][N] -> bf16 [N][K]) in ONE launch.
// 32x32 tiles; flat grid 12288 blocks decodes (job, ktile, ntile).
// ---------------------------------------------------------------------------
__global__ __launch_bounds__(256) void convt_all(const float* __restrict__ Wq,
                                                 const float* __restrict__ Wk,
                                                 const float* __restrict__ Wv,
                                                 const float* __restrict__ Wo,
                                                 const float* __restrict__ W1,
                                                 const float* __restrict__ W2,
                                                 __bf16* __restrict__ BtQKV,
                                                 __bf16* __restrict__ BtO,
                                                 __bf16* __restrict__ Bt1,
                                                 __bf16* __restrict__ Bt2) {
    __shared__ float t[32][33];
    int id = blockIdx.x;
    const float* in; __bf16* out; int K, N, nt, kt;
    if (id < 4096) {
        int job = id >> 10, tt = id & 1023;
        nt = tt & 31; kt = tt >> 5; K = 1024; N = 1024;
        if (job == 0)      { in = Wq; out = BtQKV; }
        else if (job == 1) { in = Wk; out = BtQKV + 1024 * 1024; }
        else if (job == 2) { in = Wv; out = BtQKV + 2 * 1024 * 1024; }
        else               { in = Wo; out = BtO; }
    } else if (id < 8192) {
        int tt = id - 4096;
        nt = tt & 127; kt = tt >> 7; K = 1024; N = 4096; in = W1; out = Bt1;
    } else {
        int tt = id - 8192;
        nt = tt & 31; kt = tt >> 5; K = 4096; N = 1024; in = W2; out = Bt2;
    }
    int n0 = nt * 32, k0 = kt * 32;
    int r  = threadIdx.x >> 3;
    int c4 = (threadIdx.x & 7) * 4;
    float4 v = *(const float4*)(in + (size_t)(k0 + r) * N + n0 + c4);
    t[r][c4 + 0] = v.x; t[r][c4 + 1] = v.y; t[r][c4 + 2] = v.z; t[r][c4 + 3] = v.w;
    __syncthreads();
    bf16x4 o;
    o[0] = (__bf16)t[c4 + 0][r];
    o[1] = (__bf16)t[c4 + 1][r];
    o[2] = (__bf16)t[c4 + 2][r];
    o[3] = (__bf16)t[c4 + 3][r];
    *(bf16x4*)(out + (size_t)(n0 + r) * K + k0 + c4) = o;
}

// ---------------------------------------------------------------------------
// Shared MFMA core: acc[4][4] += A[128 rows @ m0] * Bt[128 rows @ n0]^T
// over Klen (row stride Kstride). m97 structure, BK=32.
// ---------------------------------------------------------------------------
__device__ __forceinline__ void mfma_core128(const __bf16* __restrict__ A,
                                             const __bf16* __restrict__ Bt,
                                             int Kstride, int Klen,
                                             int m0, int n0, int tid,
                                             floatx4 (&acc)[4][4]) {
    __shared__ __bf16 As[128 * 32];
    __shared__ __bf16 Bs[128 * 32];
    int lane = tid & 63;
    int wave = tid >> 6;
    int wr = wave >> 1, wc = wave & 1;

    int sr = lane >> 2;
    int sk = (lane & 3) * 8;
    const __bf16* ga0 = A  + (size_t)(m0 + wave * 16 + sr) * Kstride + sk;
    const __bf16* ga1 = ga0 + (size_t)64 * Kstride;
    const __bf16* gb0 = Bt + (size_t)(n0 + wave * 16 + sr) * Kstride + sk;
    const __bf16* gb1 = gb0 + (size_t)64 * Kstride;
    __bf16* la0 = &As[wave * 512];
    __bf16* la1 = &As[2048 + wave * 512];
    __bf16* lb0 = &Bs[wave * 512];
    __bf16* lb1 = &Bs[2048 + wave * 512];

    int fm = lane & 15;
    int fk = (lane >> 4) * 8;

    for (int k0 = 0; k0 < Klen; k0 += 32) {
        __builtin_amdgcn_global_load_lds(AS1(ga0 + k0), AS3(la0), 16, 0, 0);
        __builtin_amdgcn_global_load_lds(AS1(ga1 + k0), AS3(la1), 16, 0, 0);
        __builtin_amdgcn_global_load_lds(AS1(gb0 + k0), AS3(lb0), 16, 0, 0);
        __builtin_amdgcn_global_load_lds(AS1(gb1 + k0), AS3(lb1), 16, 0, 0);
        __syncthreads();

        bf16x8 af[4], bfv[4];
#pragma unroll
        for (int i = 0; i < 4; i++)
            af[i] = *(const bf16x8*)(As + (size_t)(wr * 64 + i * 16 + fm) * 32 + fk);
#pragma unroll
        for (int j = 0; j < 4; j++)
            bfv[j] = *(const bf16x8*)(Bs + (size_t)(wc * 64 + j * 16 + fm) * 32 + fk);
#pragma unroll
        for (int i = 0; i < 4; i++)
#pragma unroll
            for (int j = 0; j < 4; j++)
                acc[i][j] = __builtin_amdgcn_mfma_f32_16x16x32_bf16(
                    af[i], bfv[j], acc[i][j], 0, 0, 0);
        __syncthreads();
    }
}

// ---------------------------------------------------------------------------
// Full-K GEMM with epilogue: C = A*Bt^T (+bias)(+relu)(+res)
// ---------------------------------------------------------------------------
template <typename OutT, bool BIAS, bool RELU, bool RES>
__global__ __launch_bounds__(256) void mgemm(const __bf16* __restrict__ A,
                                             const __bf16* __restrict__ Bt,
                                             const float* __restrict__ bias,
                                             const float* __restrict__ res,
                                             OutT* __restrict__ C,
                                             int M, int N, int Kstride, int Klen) {
    int tid = threadIdx.x;
    int lane = tid & 63;
    int wave = tid >> 6;
    int m0 = blockIdx.y * 128, n0 = blockIdx.x * 128;
    int wr = wave >> 1, wc = wave & 1;
    floatx4 acc[4][4] = {};
    mfma_core128(A, Bt, Kstride, Klen, m0, n0, tid, acc);

#pragma unroll
    for (int i = 0; i < 4; i++) {
#pragma unroll
        for (int j = 0; j < 4; j++) {
            int row = m0 + wr * 64 + i * 16 + (lane >> 4) * 4;
            int col = n0 + wc * 64 + j * 16 + (lane & 15);
#pragma unroll
            for (int r = 0; r < 4; r++) {
                float v = acc[i][j][r];
                if (BIAS) v += bias[col];
                if (RELU) v = fmaxf(v, 0.0f);
                if (RES)  v += res[(size_t)(row + r) * N + col];
                C[(size_t)(row + r) * N + col] = (OutT)v;
            }
        }
    }
}

// ---------------------------------------------------------------------------
// Split-K GEMM: blockIdx.z picks K-chunk; writes bf16 partial tile.
// Partial z<3 at P0 + z*M*N; z==3 at P3 (ws regions are non-contiguous).
// ---------------------------------------------------------------------------
__global__ __launch_bounds__(256) void mgemm_sk(const __bf16* __restrict__ A,
                                                const __bf16* __restrict__ Bt,
                                                __bf16* __restrict__ P0,
                                                __bf16* __restrict__ P3,
                                                int M, int N, int Kstride, int Klen) {
    int z = blockIdx.z;
    const __bf16* Az  = A  + (size_t)z * Klen;
    const __bf16* Btz = Bt + (size_t)z * Klen;
    __bf16* C = (z == 3) ? P3 : (P0 + (size_t)z * M * N);

    int tid = threadIdx.x;
    int lane = tid & 63;
    int wave = tid >> 6;
    int m0 = blockIdx.y * 128, n0 = blockIdx.x * 128;
    int wr = wave >> 1, wc = wave & 1;
    floatx4 acc[4][4] = {};
    mfma_core128(Az, Btz, Kstride, Klen, m0, n0, tid, acc);

#pragma unroll
    for (int i = 0; i < 4; i++) {
#pragma unroll
        for (int j = 0; j < 4; j++) {
            int row = m0 + wr * 64 + i * 16 + (lane >> 4) * 4;
            int col = n0 + wc * 64 + j * 16 + (lane & 15);
#pragma unroll
            for (int r = 0; r < 4; r++)
                C[(size_t)(row + r) * N + col] = (__bf16)acc[i][j][r];
        }
    }
}

// ---------------------------------------------------------------------------
// Reductions. 8 elems/thread.
// red_wo: out = emb + p0 + p1                (Wo path, fp32 out)
// red_w2: out += p0+p1+p2+p3 + b2[col]      (W2 path, in-place on out)
// ---------------------------------------------------------------------------
__global__ __launch_bounds__(256) void red_wo(const float* __restrict__ emb,
                                              const __bf16* __restrict__ p0,
                                              const __bf16* __restrict__ p1,
                                              float* __restrict__ out) {
    size_t i = ((size_t)blockIdx.x * 256 + threadIdx.x) * 8;
    bf16x8 a = *(const bf16x8*)(p0 + i);
    bf16x8 b = *(const bf16x8*)(p1 + i);
    float4 e0 = *(const float4*)(emb + i);
    float4 e1 = *(const float4*)(emb + i + 4);
    float4 o0, o1;
    o0.x = e0.x + (float)a[0] + (float)b[0];
    o0.y = e0.y + (float)a[1] + (float)b[1];
    o0.z = e0.z + (float)a[2] + (float)b[2];
    o0.w = e0.w + (float)a[3] + (float)b[3];
    o1.x = e1.x + (float)a[4] + (float)b[4];
    o1.y = e1.y + (float)a[5] + (float)b[5];
    o1.z = e1.z + (float)a[6] + (float)b[6];
    o1.w = e1.w + (float)a[7] + (float)b[7];
    *(float4*)(out + i)     = o0;
    *(float4*)(out + i + 4) = o1;
}

__global__ __launch_bounds__(256) void red_w2(const __bf16* __restrict__ p0,
                                              const __bf16* __restrict__ p3,
                                              const float* __restrict__ b2,
                                              float* __restrict__ out,
                                              int N) {
    size_t i = ((size_t)blockIdx.x * 256 + threadIdx.x) * 8;
    const size_t MN = (size_t)ROWS * HIDDEN;
    bf16x8 a = *(const bf16x8*)(p0 + i);
    bf16x8 b = *(const bf16x8*)(p0 + MN + i);
    bf16x8 c = *(const bf16x8*)(p0 + 2 * MN + i);
    bf16x8 d = *(const bf16x8*)(p3 + i);
    int col = (int)(i & (size_t)(N - 1));
    float4 bb0 = *(const float4*)(b2 + col);
    float4 bb1 = *(const float4*)(b2 + col + 4);
    float4 o0 = *(const float4*)(out + i);
    float4 o1 = *(const float4*)(out + i + 4);
    o0.x += (float)a[0] + (float)b[0] + (float)c[0] + (float)d[0] + bb0.x;
    o0.y += (float)a[1] + (float)b[1] + (float)c[1] + (float)d[1] + bb0.y;
    o0.z += (float)a[2] + (float)b[2] + (float)c[2] + (float)d[2] + bb0.z;
    o0.w += (float)a[3] + (float)b[3] + (float)c[3] + (float)d[3] + bb0.w;
    o1.x += (float)a[4] + (float)b[4] + (float)c[4] + (float)d[4] + bb1.x;
    o1.y += (float)a[5] + (float)b[5] + (float)c[5] + (float)d[5] + bb1.y;
    o1.z += (float)a[6] + (float)b[6] + (float)c[6] + (float)d[6] + bb1.z;
    o1.w += (float)a[7] + (float)b[7] + (float)c[7] + (float)d[7] + bb1.w;
    *(float4*)(out + i)     = o0;
    *(float4*)(out + i + 4) = o1;
}

// ---------------------------------------------------------------------------
// V transpose: qkv v-part [B*T][3H] -> Vt[bh][d][T]   (64x64 LDS tiles)
// ---------------------------------------------------------------------------
__global__ __launch_bounds__(256) void vtrans(const __bf16* __restrict__ qkv,
                                              __bf16* __restrict__ Vt) {
    __shared__ __bf16 t[64 * 64];
    int bh = blockIdx.x, b = bh >> 4, h = bh & 15;
    int t0 = blockIdx.y * 64;
    int tid = threadIdx.x;
    int lt = tid >> 2;
    int ds = (tid & 3) * 16;
    const __bf16* vp = qkv + (size_t)(b * SEQ + t0 + lt) * (3 * HIDDEN)
                     + 2 * HIDDEN + h * HDIM + ds;
    bf16x8 a = *(const bf16x8*)vp;
    bf16x8 c = *(const bf16x8*)(vp + 8);
#pragma unroll
    for (int i = 0; i < 8; i++) {
        int d0 = ds + i, d1 = ds + 8 + i;
        t[d0 * 64 + SWZ(d0, lt >> 3) + (lt & 7)] = a[i];
        t[d1 * 64 + SWZ(d1, lt >> 3) + (lt & 7)] = c[i];
    }
    __syncthreads();
    int dr = tid >> 2;
    int c2 = (tid & 3) * 2;
    bf16x8 o0 = *(const bf16x8*)&t[dr * 64 + SWZ(dr, c2)];
    bf16x8 o1 = *(const bf16x8*)&t[dr * 64 + SWZ(dr, c2 + 1)];
    __bf16* op = Vt + ((size_t)bh * HDIM + dr) * SEQ + t0;
    *(bf16x8*)(op + c2 * 8)     = o0;
    *(bf16x8*)(op + c2 * 8 + 8) = o1;
}

// ---------------------------------------------------------------------------
// MFMA flash attention (verified R3 structure).
// ---------------------------------------------------------------------------
__global__ __launch_bounds__(256) void attn_mfma(const __bf16* __restrict__ qkv,
                                                 const __bf16* __restrict__ Vt,
                                                 __bf16* __restrict__ ctx) {
    __shared__ __bf16 Ks[64 * 64];
    __shared__ __bf16 Vs[64 * 64];
    __shared__ __bf16 Ps[4][16 * 64];
    const int QKVW = 3 * HIDDEN;

    int bh = blockIdx.x;
    int qt = gridDim.y - 1 - blockIdx.y;
    int b = bh >> 4, h = bh & 15;
    int tid = threadIdx.x;
    int lane = tid & 63;
    int w = tid >> 6;
    int m = lane & 15;
    int g = lane >> 4;

    bf16x8 qf[2];
    {
        const __bf16* Qp = qkv + (size_t)(b * SEQ + qt * 64 + w * 16 + m) * QKVW
                         + h * HDIM + g * 8;
        qf[0] = *(const bf16x8*)(Qp);
        qf[1] = *(const bf16x8*)(Qp + 32);
#pragma unroll
        for (int t = 0; t < 2; t++)
#pragma unroll
            for (int i = 0; i < 8; i++)
                qf[t][i] = (__bf16)((float)qf[t][i] * 0.125f);
    }

    floatx4 oacc[4] = {};
    float m_i[4], l_i[4];
#pragma unroll
    for (int r = 0; r < 4; r++) { m_i[r] = -INFINITY; l_i[r] = 0.0f; }

    int srow = tid >> 2;
    int sc0  = (tid & 3) * 2;
    const __bf16* Kg = qkv + (size_t)(b * SEQ) * QKVW + HIDDEN + h * HDIM;
    const __bf16* Vg = Vt + (size_t)bh * HDIM * SEQ;

    for (int kt = 0; kt <= qt; kt++) {
        __syncthreads();
        {
            const __bf16* kp = Kg + (size_t)(kt * 64 + srow) * QKVW + sc0 * 8;
            bf16x8 k0 = *(const bf16x8*)kp;
            bf16x8 k1 = *(const bf16x8*)(kp + 8);
            const __bf16* vp = Vg + (size_t)srow * SEQ + kt * 64 + sc0 * 8;
            bf16x8 v0 = *(const bf16x8*)vp;
            bf16x8 v1 = *(const bf16x8*)(vp + 8);
            *(bf16x8*)&Ks[srow * 64 + SWZ(srow, sc0)]     = k0;
            *(bf16x8*)&Ks[srow * 64 + SWZ(srow, sc0 + 1)] = k1;
            *(bf16x8*)&Vs[srow * 64 + SWZ(srow, sc0)]     = v0;
            *(bf16x8*)&Vs[srow * 64 + SWZ(srow, sc0 + 1)] = v1;
        }
        __syncthreads();

        floatx4 sacc[4] = {};
#pragma unroll
        for (int j = 0; j < 4; j++) {
#pragma unroll
            for (int t = 0; t < 2; t++) {
                int kr = 16 * j + m;
                bf16x8 kf = *(const bf16x8*)&Ks[kr * 64 + SWZ(kr, g + 4 * t)];
                sacc[j] = __builtin_amdgcn_mfma_f32_16x16x32_bf16(
                    qf[t], kf, sacc[j], 0, 0, 0);
            }
        }

        if (kt == qt) {
            int qlocal = w * 16 + 4 * g;
#pragma unroll
            for (int j = 0; j < 4; j++)
#pragma unroll
                for (int r = 0; r < 4; r++)
                    if (16 * j + m > qlocal + r) sacc[j][r] = -INFINITY;
        }

        float alpha[4];
#pragma unroll
        for (int r = 0; r < 4; r++) {
            float mx = fmaxf(fmaxf(sacc[0][r], sacc[1][r]),
                             fmaxf(sacc[2][r], sacc[3][r]));
            mx = fmaxf(mx, __shfl_xor(mx, 1, 64));
            mx = fmaxf(mx, __shfl_xor(mx, 2, 64));
            mx = fmaxf(mx, __shfl_xor(mx, 4, 64));
            mx = fmaxf(mx, __shfl_xor(mx, 8, 64));
            float mnew = fmaxf(m_i[r], mx);
            alpha[r] = __expf(m_i[r] - mnew);
            float ps = 0.0f;
#pragma unroll
            for (int j = 0; j < 4; j++) {
                float p = __expf(sacc[j][r] - mnew);
                sacc[j][r] = p;
                ps += p;
            }
            ps += __shfl_xor(ps, 1, 64);
            ps += __shfl_xor(ps, 2, 64);
            ps += __shfl_xor(ps, 4, 64);
            ps += __shfl_xor(ps, 8, 64);
            l_i[r] = l_i[r] * alpha[r] + ps;
            m_i[r] = mnew;
        }
#pragma unroll
        for (int jd = 0; jd < 4; jd++)
#pragma unroll
            for (int r = 0; r < 4; r++) oacc[jd][r] *= alpha[r];

        __bf16* Pw = &Ps[w][0];
#pragma unroll
        for (int j = 0; j < 4; j++)
#pragma unroll
            for (int r = 0; r < 4; r++) {
                int row = 4 * g + r;
                int key = 16 * j + m;
                Pw[row * 64 + SWZ(row, key >> 3) + (key & 7)] = (__bf16)sacc[j][r];
            }

#pragma unroll
        for (int t = 0; t < 2; t++) {
            bf16x8 pf = *(const bf16x8*)&Pw[m * 64 + SWZ(m, g + 4 * t)];
#pragma unroll
            for (int jd = 0; jd < 4; jd++) {
                int vr = 16 * jd + m;
                bf16x8 vf = *(const bf16x8*)&Vs[vr * 64 + SWZ(vr, g + 4 * t)];
                oacc[jd] = __builtin_amdgcn_mfma_f32_16x16x32_bf16(
                    pf, vf, oacc[jd], 0, 0, 0);
            }
        }
    }

#pragma unroll
    for (int r = 0; r < 4; r++) {
        float invl = 1.0f / l_i[r];
        int row = qt * 64 + w * 16 + 4 * g + r;
        __bf16* cp = ctx + (size_t)(b * SEQ + row) * HIDDEN + h * HDIM;
#pragma unroll
        for (int jd = 0; jd < 4; jd++)
            cp[16 * jd + m] = (__bf16)(oacc[jd][r] * invl);
    }
}

// ---------------------------------------------------------------------------
extern "C" void kernel_launch(void* const* d_in, const int* in_sizes, int n_in,
                              void* d_out, int out_size, void* d_ws, size_t ws_size,
                              hipStream_t stream) {
    (void)in_sizes; (void)n_in; (void)out_size; (void)ws_size;
    const float* emb = (const float*)d_in[0];
    const float* Wq  = (const float*)d_in[1];
    const float* Wk  = (const float*)d_in[2];
    const float* Wv  = (const float*)d_in[3];
    const float* Wo  = (const float*)d_in[4];
    const float* W1  = (const float*)d_in[5];
    const float* b1  = (const float*)d_in[6];
    const float* W2  = (const float*)d_in[7];
    const float* b2  = (const float*)d_in[8];
    const float* g1  = (const float*)d_in[9];
    const float* be1 = (const float*)d_in[10];
    const float* g2  = (const float*)d_in[11];
    const float* be2 = (const float*)d_in[12];
    float* out = (float*)d_out;

    // ws layout (bf16 elems; ME = 1M elems = 2MB). Total 36 ME = 72 MB.
    //   [0,4)   h (LN1) -> ctx (attn out) -> ff1 head
    //   [4,16)  qkv (dead after attn) -> Wo partials [4,12)
    //   [0,16)  ff1 (after red_wo+ln2)
    //   [16,20) h2 (dead after W1 gemm) -> W2 partial z0
    //   [20,23) BtQKV  [23,24) BtO  -> W2 partial z1 after their gemms
    //   [24,28) Bt1 -> W2 partial z2
    //   [28,32) Bt2 (alive through W2 gemm)
    //   [32,36) Vt (dead after attn) -> W2 partial z3
    __bf16* wsb = (__bf16*)d_ws;
    const size_t ME = 1024 * 1024;
    __bf16* h     = wsb;
    __bf16* qkv   = wsb + 4 * ME;
    __bf16* ctx   = wsb;
    __bf16* ff1   = wsb;
    __bf16* h2    = wsb + 16 * ME;
    __bf16* BtQKV = wsb + 20 * ME;
    __bf16* BtO   = wsb + 23 * ME;
    __bf16* Bt1   = wsb + 24 * ME;
    __bf16* Bt2   = wsb + 28 * ME;
    __bf16* Vt    = wsb + 32 * ME;
    __bf16* woP   = wsb + 4 * ME;    // 2 x 4 ME
    __bf16* w2P0  = wsb + 16 * ME;   // z0..z2 contiguous (12 ME)
    __bf16* w2P3  = wsb + 32 * ME;   // z3

    convt_all<<<12288, 256, 0, stream>>>(Wq, Wk, Wv, Wo, W1, W2,
                                         BtQKV, BtO, Bt1, Bt2);

    ln_kernel<<<ROWS, 256, 0, stream>>>(emb, g1, be1, h);

    mgemm<__bf16, false, false, false><<<dim3(24, 32), 256, 0, stream>>>(
        h, BtQKV, nullptr, nullptr, qkv, ROWS, 3072, 1024, 1024);

    vtrans<<<dim3(32, 32), 256, 0, stream>>>(qkv, Vt);

    attn_mfma<<<dim3(32, 32), 256, 0, stream>>>(qkv, Vt, ctx);

    // Wo split-K x2: partials = ctx @ BtO^T over K halves
    mgemm_sk<<<dim3(8, 32, 2), 256, 0, stream>>>(
        ctx, BtO, woP, nullptr, ROWS, 1024, 1024, 512);
    // out = emb + p0 + p1
    red_wo<<<2048, 256, 0, stream>>>(emb, woP, woP + 4 * ME, out);

    ln_kernel<<<ROWS, 256, 0, stream>>>(out, g2, be2, h2);

    mgemm<__bf16, true, true, false><<<dim3(32, 32), 256, 0, stream>>>(
        h2, Bt1, b1, nullptr, ff1, ROWS, 4096, 1024, 1024);

    // W2 split-K x4
    mgemm_sk<<<dim3(8, 32, 4), 256, 0, stream>>>(
        ff1, Bt2, w2P0, w2P3, ROWS, 1024, 4096, 1024);
    // out += sum(partials) + b2
    red_w2<<<2048, 256, 0, stream>>>(w2P0, w2P3, b2, out, 1024);
}

// Round 5
// 372.813 us; speedup vs baseline: 5.1509x; 1.0514x over previous
//
#include <hip/hip_runtime.h>
#include <math.h>

#define HIDDEN 1024
#define SEQ    2048
#define NHEAD  16
#define HDIM   64
#define ROWS   (2 * SEQ)

typedef float  floatx4 __attribute__((ext_vector_type(4)));
typedef __bf16 bf16x8  __attribute__((ext_vector_type(8)));
typedef __bf16 bf16x4  __attribute__((ext_vector_type(4)));

#define AS1(p) ((const __attribute__((address_space(1))) void*)(p))
#define AS3(p) ((__attribute__((address_space(3))) void*)(p))

// swizzled byte-chunk offset (in elements): 16B chunks XOR'd by row&7
#define SWZ(row, chunk) ((((chunk) ^ ((row) & 7)) * 8))

// ---------------------------------------------------------------------------
// LayerNorm: fp32 in -> bf16 out. One block per row, 256 threads x 4 elems.
// ---------------------------------------------------------------------------
__global__ __launch_bounds__(256) void ln_kernel(const float* __restrict__ x,
                                                 const float* __restrict__ g,
                                                 const float* __restrict__ beta,
                                                 __bf16* __restrict__ out) {
    int row = blockIdx.x;
    int tid = threadIdx.x;
    const float* xr = x + (size_t)row * HIDDEN;
    float4 v = *(const float4*)(xr + tid * 4);
    float s  = v.x + v.y + v.z + v.w;
    float s2 = v.x * v.x + v.y * v.y + v.z * v.z + v.w * v.w;
#pragma unroll
    for (int off = 1; off < 64; off <<= 1) {
        s  += __shfl_xor(s, off, 64);
        s2 += __shfl_xor(s2, off, 64);
    }
    __shared__ float red[8];
    int wid = tid >> 6;
    if ((tid & 63) == 0) { red[wid] = s; red[wid + 4] = s2; }
    __syncthreads();
    s  = red[0] + red[1] + red[2] + red[3];
    s2 = red[4] + red[5] + red[6] + red[7];
    float mu  = s * (1.0f / HIDDEN);
    float var = fmaxf(s2 * (1.0f / HIDDEN) - mu * mu, 0.0f);
    float inv = rsqrtf(var + 1e-5f);
    float4 gv = *(const float4*)(g + tid * 4);
    float4 bv = *(const float4*)(beta + tid * 4);
    bf16x4 o;
    o[0] = (__bf16)((v.x - mu) * inv * gv.x + bv.x);
    o[1] = (__bf16)((v.y - mu) * inv * gv.y + bv.y);
    o[2] = (__bf16)((v.z - mu) * inv * gv.z + bv.z);
    o[3] = (__bf16)((v.w - mu) * inv * gv.w + bv.w);
    *(bf16x4*)(out + (size_t)row * HIDDEN + tid * 4) = o;
}

// ---------------------------------------------------------------------------
// Fused Wo-split-K reduction + residual + LayerNorm2.
// One block per row: x1 = emb + p0 + p1 -> out (fp32), h2 = LN(x1) (bf16).
// ---------------------------------------------------------------------------
__global__ __launch_bounds__(256) void red_wo_ln(const float* __restrict__ emb,
                                                 const __bf16* __restrict__ p0,
                                                 const __bf16* __restrict__ p1,
                                                 const float* __restrict__ g,
                                                 const float* __restrict__ beta,
                                                 float* __restrict__ out,
                                                 __bf16* __restrict__ h2) {
    int row = blockIdx.x;
    int tid = threadIdx.x;
    size_t i = (size_t)row * HIDDEN + tid * 4;
    float4 e = *(const float4*)(emb + i);
    bf16x4 a = *(const bf16x4*)(p0 + i);
    bf16x4 b = *(const bf16x4*)(p1 + i);
    float4 v;
    v.x = e.x + (float)a[0] + (float)b[0];
    v.y = e.y + (float)a[1] + (float)b[1];
    v.z = e.z + (float)a[2] + (float)b[2];
    v.w = e.w + (float)a[3] + (float)b[3];
    *(float4*)(out + i) = v;

    float s  = v.x + v.y + v.z + v.w;
    float s2 = v.x * v.x + v.y * v.y + v.z * v.z + v.w * v.w;
#pragma unroll
    for (int off = 1; off < 64; off <<= 1) {
        s  += __shfl_xor(s, off, 64);
        s2 += __shfl_xor(s2, off, 64);
    }
    __shared__ float red[8];
    int wid = tid >> 6;
    if ((tid & 63) == 0) { red[wid] = s; red[wid + 4] = s2; }
    __syncthreads();
    s  = red[0] + red[1] + red[2] + red[3];
    s2 = red[4] + red[5] + red[6] + red[7];
    float mu  = s * (1.0f / HIDDEN);
    float var = fmaxf(s2 * (1.0f / HIDDEN) - mu * mu, 0.0f);
    float inv = rsqrtf(var + 1e-5f);
    float4 gv = *(const float4*)(g + tid * 4);
    float4 bv = *(const float4*)(beta + tid * 4);
    bf16x4 o;
    o[0] = (__bf16)((v.x - mu) * inv * gv.x + bv.x);
    o[1] = (__bf16)((v.y - mu) * inv * gv.y + bv.y);
    o[2] = (__bf16)((v.z - mu) * inv * gv.z + bv.z);
    o[3] = (__bf16)((v.w - mu) * inv * gv.w + bv.w);
    *(bf16x4*)(h2 + i) = o;
}

// ---------------------------------------------------------------------------
// All weight converts (fp32 [K][N] -> bf16 [N][K]) in ONE launch.
// ---------------------------------------------------------------------------
__global__ __launch_bounds__(256) void convt_all(const float* __restrict__ Wq,
                                                 const float* __restrict__ Wk,
                                                 const float* __restrict__ Wv,
                                                 const float* __restrict__ Wo,
                                                 const float* __restrict__ W1,
                                                 const float* __restrict__ W2,
                                                 __bf16* __restrict__ BtQKV,
                                                 __bf16* __restrict__ BtO,
                                                 __bf16* __restrict__ Bt1,
                                                 __bf16* __restrict__ Bt2) {
    __shared__ float t[32][33];
    int id = blockIdx.x;
    const float* in; __bf16* out; int K, N, nt, kt;
    if (id < 4096) {
        int job = id >> 10, tt = id & 1023;
        nt = tt & 31; kt = tt >> 5; K = 1024; N = 1024;
        if (job == 0)      { in = Wq; out = BtQKV; }
        else if (job == 1) { in = Wk; out = BtQKV + 1024 * 1024; }
        else if (job == 2) { in = Wv; out = BtQKV + 2 * 1024 * 1024; }
        else               { in = Wo; out = BtO; }
    } else if (id < 8192) {
        int tt = id - 4096;
        nt = tt & 127; kt = tt >> 7; K = 1024; N = 4096; in = W1; out = Bt1;
    } else {
        int tt = id - 8192;
        nt = tt & 31; kt = tt >> 5; K = 4096; N = 1024; in = W2; out = Bt2;
    }
    int n0 = nt * 32, k0 = kt * 32;
    int r  = threadIdx.x >> 3;
    int c4 = (threadIdx.x & 7) * 4;
    float4 v = *(const float4*)(in + (size_t)(k0 + r) * N + n0 + c4);
    t[r][c4 + 0] = v.x; t[r][c4 + 1] = v.y; t[r][c4 + 2] = v.z; t[r][c4 + 3] = v.w;
    __syncthreads();
    bf16x4 o;
    o[0] = (__bf16)t[c4 + 0][r];
    o[1] = (__bf16)t[c4 + 1][r];
    o[2] = (__bf16)t[c4 + 2][r];
    o[3] = (__bf16)t[c4 + 3][r];
    *(bf16x4*)(out + (size_t)(n0 + r) * K + k0 + c4) = o;
}

// ---------------------------------------------------------------------------
// Shared MFMA core (m97 structure, BK=32).
// ---------------------------------------------------------------------------
__device__ __forceinline__ void mfma_core128(const __bf16* __restrict__ A,
                                             const __bf16* __restrict__ Bt,
                                             int Kstride, int Klen,
                                             int m0, int n0, int tid,
                                             floatx4 (&acc)[4][4]) {
    __shared__ __bf16 As[128 * 32];
    __shared__ __bf16 Bs[128 * 32];
    int lane = tid & 63;
    int wave = tid >> 6;
    int wr = wave >> 1, wc = wave & 1;

    int sr = lane >> 2;
    int sk = (lane & 3) * 8;
    const __bf16* ga0 = A  + (size_t)(m0 + wave * 16 + sr) * Kstride + sk;
    const __bf16* ga1 = ga0 + (size_t)64 * Kstride;
    const __bf16* gb0 = Bt + (size_t)(n0 + wave * 16 + sr) * Kstride + sk;
    const __bf16* gb1 = gb0 + (size_t)64 * Kstride;
    __bf16* la0 = &As[wave * 512];
    __bf16* la1 = &As[2048 + wave * 512];
    __bf16* lb0 = &Bs[wave * 512];
    __bf16* lb1 = &Bs[2048 + wave * 512];

    int fm = lane & 15;
    int fk = (lane >> 4) * 8;

    for (int k0 = 0; k0 < Klen; k0 += 32) {
        __builtin_amdgcn_global_load_lds(AS1(ga0 + k0), AS3(la0), 16, 0, 0);
        __builtin_amdgcn_global_load_lds(AS1(ga1 + k0), AS3(la1), 16, 0, 0);
        __builtin_amdgcn_global_load_lds(AS1(gb0 + k0), AS3(lb0), 16, 0, 0);
        __builtin_amdgcn_global_load_lds(AS1(gb1 + k0), AS3(lb1), 16, 0, 0);
        __syncthreads();

        bf16x8 af[4], bfv[4];
#pragma unroll
        for (int i = 0; i < 4; i++)
            af[i] = *(const bf16x8*)(As + (size_t)(wr * 64 + i * 16 + fm) * 32 + fk);
#pragma unroll
        for (int j = 0; j < 4; j++)
            bfv[j] = *(const bf16x8*)(Bs + (size_t)(wc * 64 + j * 16 + fm) * 32 + fk);
#pragma unroll
        for (int i = 0; i < 4; i++)
#pragma unroll
            for (int j = 0; j < 4; j++)
                acc[i][j] = __builtin_amdgcn_mfma_f32_16x16x32_bf16(
                    af[i], bfv[j], acc[i][j], 0, 0, 0);
        __syncthreads();
    }
}

// ---------------------------------------------------------------------------
// Full-K GEMM with epilogue.
// ---------------------------------------------------------------------------
template <typename OutT, bool BIAS, bool RELU, bool RES>
__global__ __launch_bounds__(256) void mgemm(const __bf16* __restrict__ A,
                                             const __bf16* __restrict__ Bt,
                                             const float* __restrict__ bias,
                                             const float* __restrict__ res,
                                             OutT* __restrict__ C,
                                             int M, int N, int Kstride, int Klen) {
    int tid = threadIdx.x;
    int lane = tid & 63;
    int wave = tid >> 6;
    int m0 = blockIdx.y * 128, n0 = blockIdx.x * 128;
    int wr = wave >> 1, wc = wave & 1;
    floatx4 acc[4][4] = {};
    mfma_core128(A, Bt, Kstride, Klen, m0, n0, tid, acc);

#pragma unroll
    for (int i = 0; i < 4; i++) {
#pragma unroll
        for (int j = 0; j < 4; j++) {
            int row = m0 + wr * 64 + i * 16 + (lane >> 4) * 4;
            int col = n0 + wc * 64 + j * 16 + (lane & 15);
#pragma unroll
            for (int r = 0; r < 4; r++) {
                float v = acc[i][j][r];
                if (BIAS) v += bias[col];
                if (RELU) v = fmaxf(v, 0.0f);
                if (RES)  v += res[(size_t)(row + r) * N + col];
                C[(size_t)(row + r) * N + col] = (OutT)v;
            }
        }
    }
}

// ---------------------------------------------------------------------------
// Split-K GEMM: blockIdx.z picks K-chunk; writes bf16 partial tile.
// ---------------------------------------------------------------------------
__global__ __launch_bounds__(256) void mgemm_sk(const __bf16* __restrict__ A,
                                                const __bf16* __restrict__ Bt,
                                                __bf16* __restrict__ P0,
                                                __bf16* __restrict__ P3,
                                                int M, int N, int Kstride, int Klen) {
    int z = blockIdx.z;
    const __bf16* Az  = A  + (size_t)z * Klen;
    const __bf16* Btz = Bt + (size_t)z * Klen;
    __bf16* C = (z == 3) ? P3 : (P0 + (size_t)z * M * N);

    int tid = threadIdx.x;
    int lane = tid & 63;
    int wave = tid >> 6;
    int m0 = blockIdx.y * 128, n0 = blockIdx.x * 128;
    int wr = wave >> 1, wc = wave & 1;
    floatx4 acc[4][4] = {};
    mfma_core128(Az, Btz, Kstride, Klen, m0, n0, tid, acc);

#pragma unroll
    for (int i = 0; i < 4; i++) {
#pragma unroll
        for (int j = 0; j < 4; j++) {
            int row = m0 + wr * 64 + i * 16 + (lane >> 4) * 4;
            int col = n0 + wc * 64 + j * 16 + (lane & 15);
#pragma unroll
            for (int r = 0; r < 4; r++)
                C[(size_t)(row + r) * N + col] = (__bf16)acc[i][j][r];
        }
    }
}

// ---------------------------------------------------------------------------
// W2 reduction: out += p0+p1+p2+p3 + b2[col]  (in-place on out)
// ---------------------------------------------------------------------------
__global__ __launch_bounds__(256) void red_w2(const __bf16* __restrict__ p0,
                                              const __bf16* __restrict__ p3,
                                              const float* __restrict__ b2,
                                              float* __restrict__ out,
                                              int N) {
    size_t i = ((size_t)blockIdx.x * 256 + threadIdx.x) * 8;
    const size_t MN = (size_t)ROWS * HIDDEN;
    bf16x8 a = *(const bf16x8*)(p0 + i);
    bf16x8 b = *(const bf16x8*)(p0 + MN + i);
    bf16x8 c = *(const bf16x8*)(p0 + 2 * MN + i);
    bf16x8 d = *(const bf16x8*)(p3 + i);
    int col = (int)(i & (size_t)(N - 1));
    float4 bb0 = *(const float4*)(b2 + col);
    float4 bb1 = *(const float4*)(b2 + col + 4);
    float4 o0 = *(const float4*)(out + i);
    float4 o1 = *(const float4*)(out + i + 4);
    o0.x += (float)a[0] + (float)b[0] + (float)c[0] + (float)d[0] + bb0.x;
    o0.y += (float)a[1] + (float)b[1] + (float)c[1] + (float)d[1] + bb0.y;
    o0.z += (float)a[2] + (float)b[2] + (float)c[2] + (float)d[2] + bb0.z;
    o0.w += (float)a[3] + (float)b[3] + (float)c[3] + (float)d[3] + bb0.w;
    o1.x += (float)a[4] + (float)b[4] + (float)c[4] + (float)d[4] + bb1.x;
    o1.y += (float)a[5] + (float)b[5] + (float)c[5] + (float)d[5] + bb1.y;
    o1.z += (float)a[6] + (float)b[6] + (float)c[6] + (float)d[6] + bb1.z;
    o1.w += (float)a[7] + (float)b[7] + (float)c[7] + (float)d[7] + bb1.w;
    *(float4*)(out + i)     = o0;
    *(float4*)(out + i + 4) = o1;
}

// ---------------------------------------------------------------------------
// V transpose: qkv v-part [B*T][3H] -> Vt[bh][d][T]   (64x64 LDS tiles)
// ---------------------------------------------------------------------------
__global__ __launch_bounds__(256) void vtrans(const __bf16* __restrict__ qkv,
                                              __bf16* __restrict__ Vt) {
    __shared__ __bf16 t[64 * 64];
    int bh = blockIdx.x, b = bh >> 4, h = bh & 15;
    int t0 = blockIdx.y * 64;
    int tid = threadIdx.x;
    int lt = tid >> 2;
    int ds = (tid & 3) * 16;
    const __bf16* vp = qkv + (size_t)(b * SEQ + t0 + lt) * (3 * HIDDEN)
                     + 2 * HIDDEN + h * HDIM + ds;
    bf16x8 a = *(const bf16x8*)vp;
    bf16x8 c = *(const bf16x8*)(vp + 8);
#pragma unroll
    for (int i = 0; i < 8; i++) {
        int d0 = ds + i, d1 = ds + 8 + i;
        t[d0 * 64 + SWZ(d0, lt >> 3) + (lt & 7)] = a[i];
        t[d1 * 64 + SWZ(d1, lt >> 3) + (lt & 7)] = c[i];
    }
    __syncthreads();
    int dr = tid >> 2;
    int c2 = (tid & 3) * 2;
    bf16x8 o0 = *(const bf16x8*)&t[dr * 64 + SWZ(dr, c2)];
    bf16x8 o1 = *(const bf16x8*)&t[dr * 64 + SWZ(dr, c2 + 1)];
    __bf16* op = Vt + ((size_t)bh * HDIM + dr) * SEQ + t0;
    *(bf16x8*)(op + c2 * 8)     = o0;
    *(bf16x8*)(op + c2 * 8 + 8) = o1;
}

// ---------------------------------------------------------------------------
// MFMA flash attention v2: no-max softmax (l >= 1 guaranteed by diagonal),
// exp2 with log2(e)/8 folded into Q scale, l accumulated via ones-MFMA.
// ---------------------------------------------------------------------------
__global__ __launch_bounds__(256) void attn_mfma(const __bf16* __restrict__ qkv,
                                                 const __bf16* __restrict__ Vt,
                                                 __bf16* __restrict__ ctx) {
    __shared__ __bf16 Ks[64 * 64];
    __shared__ __bf16 Vs[64 * 64];
    __shared__ __bf16 Ps[4][16 * 64];
    const int QKVW = 3 * HIDDEN;

    int bh = blockIdx.x;
    int qt = gridDim.y - 1 - blockIdx.y;   // heavy q-tiles dispatch first
    int b = bh >> 4, h = bh & 15;
    int tid = threadIdx.x;
    int lane = tid & 63;
    int w = tid >> 6;
    int m = lane & 15;
    int g = lane >> 4;

    // Q fragments, pre-scaled by log2(e)/8 so scores are exp2-ready
    const float QSC = 1.44269504f / 8.0f;
    bf16x8 qf[2];
    {
        const __bf16* Qp = qkv + (size_t)(b * SEQ + qt * 64 + w * 16 + m) * QKVW
                         + h * HDIM + g * 8;
        qf[0] = *(const bf16x8*)(Qp);
        qf[1] = *(const bf16x8*)(Qp + 32);
#pragma unroll
        for (int t = 0; t < 2; t++)
#pragma unroll
            for (int i = 0; i < 8; i++)
                qf[t][i] = (__bf16)((float)qf[t][i] * QSC);
    }

    bf16x8 onesf;
#pragma unroll
    for (int i = 0; i < 8; i++) onesf[i] = (__bf16)1.0f;

    floatx4 oacc[4] = {};
    floatx4 lacc = {};

    int srow = tid >> 2;
    int sc0  = (tid & 3) * 2;
    const __bf16* Kg = qkv + (size_t)(b * SEQ) * QKVW + HIDDEN + h * HDIM;
    const __bf16* Vg = Vt + (size_t)bh * HDIM * SEQ;

    for (int kt = 0; kt <= qt; kt++) {
        __syncthreads();
        {
            const __bf16* kp = Kg + (size_t)(kt * 64 + srow) * QKVW + sc0 * 8;
            bf16x8 k0 = *(const bf16x8*)kp;
            bf16x8 k1 = *(const bf16x8*)(kp + 8);
            const __bf16* vp = Vg + (size_t)srow * SEQ + kt * 64 + sc0 * 8;
            bf16x8 v0 = *(const bf16x8*)vp;
            bf16x8 v1 = *(const bf16x8*)(vp + 8);
            *(bf16x8*)&Ks[srow * 64 + SWZ(srow, sc0)]     = k0;
            *(bf16x8*)&Ks[srow * 64 + SWZ(srow, sc0 + 1)] = k1;
            *(bf16x8*)&Vs[srow * 64 + SWZ(srow, sc0)]     = v0;
            *(bf16x8*)&Vs[srow * 64 + SWZ(srow, sc0 + 1)] = v1;
        }
        __syncthreads();

        // S = (Q * log2e/8) K^T
        floatx4 sacc[4] = {};
#pragma unroll
        for (int j = 0; j < 4; j++) {
#pragma unroll
            for (int t = 0; t < 2; t++) {
                int kr = 16 * j + m;
                bf16x8 kf = *(const bf16x8*)&Ks[kr * 64 + SWZ(kr, g + 4 * t)];
                sacc[j] = __builtin_amdgcn_mfma_f32_16x16x32_bf16(
                    qf[t], kf, sacc[j], 0, 0, 0);
            }
        }

        // causal mask on the diagonal tile only (wave-uniform branch)
        if (kt == qt) {
            int qlocal = w * 16 + 4 * g;
#pragma unroll
            for (int j = 0; j < 4; j++)
#pragma unroll
                for (int r = 0; r < 4; r++)
                    if (16 * j + m > qlocal + r) sacc[j][r] = -INFINITY;
        }

        // P = exp2(S) -> per-wave-private LDS (A-layout). No max, no shuffles:
        // diagonal q.q >= 0 guarantees l >= 1; fp32 range is ample.
        __bf16* Pw = &Ps[w][0];
#pragma unroll
        for (int j = 0; j < 4; j++)
#pragma unroll
            for (int r = 0; r < 4; r++) {
                float p = exp2f(sacc[j][r]);
                int row = 4 * g + r;
                int key = 16 * j + m;
                Pw[row * 64 + SWZ(row, key >> 3) + (key & 7)] = (__bf16)p;
            }

        // O += P V ; l += P . 1  (ones-MFMA replaces shuffle reduction)
#pragma unroll
        for (int t = 0; t < 2; t++) {
            bf16x8 pf = *(const bf16x8*)&Pw[m * 64 + SWZ(m, g + 4 * t)];
            lacc = __builtin_amdgcn_mfma_f32_16x16x32_bf16(pf, onesf, lacc, 0, 0, 0);
#pragma unroll
            for (int jd = 0; jd < 4; jd++) {
                int vr = 16 * jd + m;
                bf16x8 vf = *(const bf16x8*)&Vs[vr * 64 + SWZ(vr, g + 4 * t)];
                oacc[jd] = __builtin_amdgcn_mfma_f32_16x16x32_bf16(
                    pf, vf, oacc[jd], 0, 0, 0);
            }
        }
    }

    // epilogue: O / l -> ctx [B*T][HID]
#pragma unroll
    for (int r = 0; r < 4; r++) {
        float invl = 1.0f / lacc[r];
        int row = qt * 64 + w * 16 + 4 * g + r;
        __bf16* cp = ctx + (size_t)(b * SEQ + row) * HIDDEN + h * HDIM;
#pragma unroll
        for (int jd = 0; jd < 4; jd++)
            cp[16 * jd + m] = (__bf16)(oacc[jd][r] * invl);
    }
}

// ---------------------------------------------------------------------------
extern "C" void kernel_launch(void* const* d_in, const int* in_sizes, int n_in,
                              void* d_out, int out_size, void* d_ws, size_t ws_size,
                              hipStream_t stream) {
    (void)in_sizes; (void)n_in; (void)out_size; (void)ws_size;
    const float* emb = (const float*)d_in[0];
    const float* Wq  = (const float*)d_in[1];
    const float* Wk  = (const float*)d_in[2];
    const float* Wv  = (const float*)d_in[3];
    const float* Wo  = (const float*)d_in[4];
    const float* W1  = (const float*)d_in[5];
    const float* b1  = (const float*)d_in[6];
    const float* W2  = (const float*)d_in[7];
    const float* b2  = (const float*)d_in[8];
    const float* g1  = (const float*)d_in[9];
    const float* be1 = (const float*)d_in[10];
    const float* g2  = (const float*)d_in[11];
    const float* be2 = (const float*)d_in[12];
    float* out = (float*)d_out;

    // ws layout (bf16 elems; ME = 1M elems = 2MB). Total 36 ME = 72 MB.
    //   [0,4)   h (LN1) -> ctx (attn out) -> ff1 head
    //   [4,16)  qkv (dead after attn) -> Wo partials [4,12)
    //   [0,16)  ff1 (after red_wo_ln)
    //   [16,20) h2 (dead after W1 gemm) -> W2 partial z0
    //   [20,24) BtQKV+BtO -> W2 partials z1 (after their gemms)
    //   [24,28) Bt1 -> W2 partial z2
    //   [28,32) Bt2 (alive through W2 gemm)
    //   [32,36) Vt (dead after attn) -> W2 partial z3
    __bf16* wsb = (__bf16*)d_ws;
    const size_t ME = 1024 * 1024;
    __bf16* h     = wsb;
    __bf16* qkv   = wsb + 4 * ME;
    __bf16* ctx   = wsb;
    __bf16* ff1   = wsb;
    __bf16* h2    = wsb + 16 * ME;
    __bf16* BtQKV = wsb + 20 * ME;
    __bf16* BtO   = wsb + 23 * ME;
    __bf16* Bt1   = wsb + 24 * ME;
    __bf16* Bt2   = wsb + 28 * ME;
    __bf16* Vt    = wsb + 32 * ME;
    __bf16* woP   = wsb + 4 * ME;    // 2 x 4 ME
    __bf16* w2P0  = wsb + 16 * ME;   // z0..z2 contiguous (12 ME)
    __bf16* w2P3  = wsb + 32 * ME;   // z3

    convt_all<<<12288, 256, 0, stream>>>(Wq, Wk, Wv, Wo, W1, W2,
                                         BtQKV, BtO, Bt1, Bt2);

    ln_kernel<<<ROWS, 256, 0, stream>>>(emb, g1, be1, h);

    mgemm<__bf16, false, false, false><<<dim3(24, 32), 256, 0, stream>>>(
        h, BtQKV, nullptr, nullptr, qkv, ROWS, 3072, 1024, 1024);

    vtrans<<<dim3(32, 32), 256, 0, stream>>>(qkv, Vt);

    attn_mfma<<<dim3(32, 32), 256, 0, stream>>>(qkv, Vt, ctx);

    // Wo split-K x2: partials = ctx @ BtO^T over K halves
    mgemm_sk<<<dim3(8, 32, 2), 256, 0, stream>>>(
        ctx, BtO, woP, nullptr, ROWS, 1024, 1024, 512);
    // out = emb + p0 + p1 ; h2 = LN2(out)   (fused)
    red_wo_ln<<<ROWS, 256, 0, stream>>>(emb, woP, woP + 4 * ME, g2, be2, out, h2);

    mgemm<__bf16, true, true, false><<<dim3(32, 32), 256, 0, stream>>>(
        h2, Bt1, b1, nullptr, ff1, ROWS, 4096, 1024, 1024);

    // W2 split-K x4
    mgemm_sk<<<dim3(8, 32, 4), 256, 0, stream>>>(
        ff1, Bt2, w2P0, w2P3, ROWS, 1024, 4096, 1024);
    // out += sum(partials) + b2
    red_w2<<<2048, 256, 0, stream>>>(w2P0, w2P3, b2, out, 1024);
}

// Round 6
// 362.067 us; speedup vs baseline: 5.3038x; 1.0297x over previous
//
#include <hip/hip_runtime.h>
#include <math.h>

#define HIDDEN 1024
#define SEQ    2048
#define NHEAD  16
#define HDIM   64
#define ROWS   (2 * SEQ)

typedef float  floatx4  __attribute__((ext_vector_type(4)));
typedef float  floatx16 __attribute__((ext_vector_type(16)));
typedef __bf16 bf16x8   __attribute__((ext_vector_type(8)));
typedef __bf16 bf16x4   __attribute__((ext_vector_type(4)));

#define AS1(p) ((const __attribute__((address_space(1))) void*)(p))
#define AS3(p) ((__attribute__((address_space(3))) void*)(p))

// swizzled byte-chunk offset (in elements): 16B chunks XOR'd by row&7
#define SWZ(row, chunk) ((((chunk) ^ ((row) & 7)) * 8))

// ---------------------------------------------------------------------------
// LayerNorm: fp32 in -> bf16 out. One block per row, 256 threads x 4 elems.
// ---------------------------------------------------------------------------
__global__ __launch_bounds__(256) void ln_kernel(const float* __restrict__ x,
                                                 const float* __restrict__ g,
                                                 const float* __restrict__ beta,
                                                 __bf16* __restrict__ out) {
    int row = blockIdx.x;
    int tid = threadIdx.x;
    const float* xr = x + (size_t)row * HIDDEN;
    float4 v = *(const float4*)(xr + tid * 4);
    float s  = v.x + v.y + v.z + v.w;
    float s2 = v.x * v.x + v.y * v.y + v.z * v.z + v.w * v.w;
#pragma unroll
    for (int off = 1; off < 64; off <<= 1) {
        s  += __shfl_xor(s, off, 64);
        s2 += __shfl_xor(s2, off, 64);
    }
    __shared__ float red[8];
    int wid = tid >> 6;
    if ((tid & 63) == 0) { red[wid] = s; red[wid + 4] = s2; }
    __syncthreads();
    s  = red[0] + red[1] + red[2] + red[3];
    s2 = red[4] + red[5] + red[6] + red[7];
    float mu  = s * (1.0f / HIDDEN);
    float var = fmaxf(s2 * (1.0f / HIDDEN) - mu * mu, 0.0f);
    float inv = rsqrtf(var + 1e-5f);
    float4 gv = *(const float4*)(g + tid * 4);
    float4 bv = *(const float4*)(beta + tid * 4);
    bf16x4 o;
    o[0] = (__bf16)((v.x - mu) * inv * gv.x + bv.x);
    o[1] = (__bf16)((v.y - mu) * inv * gv.y + bv.y);
    o[2] = (__bf16)((v.z - mu) * inv * gv.z + bv.z);
    o[3] = (__bf16)((v.w - mu) * inv * gv.w + bv.w);
    *(bf16x4*)(out + (size_t)row * HIDDEN + tid * 4) = o;
}

// ---------------------------------------------------------------------------
// Fused Wo-split-K reduction + residual + LayerNorm2.
// ---------------------------------------------------------------------------
__global__ __launch_bounds__(256) void red_wo_ln(const float* __restrict__ emb,
                                                 const __bf16* __restrict__ p0,
                                                 const __bf16* __restrict__ p1,
                                                 const float* __restrict__ g,
                                                 const float* __restrict__ beta,
                                                 float* __restrict__ out,
                                                 __bf16* __restrict__ h2) {
    int row = blockIdx.x;
    int tid = threadIdx.x;
    size_t i = (size_t)row * HIDDEN + tid * 4;
    float4 e = *(const float4*)(emb + i);
    bf16x4 a = *(const bf16x4*)(p0 + i);
    bf16x4 b = *(const bf16x4*)(p1 + i);
    float4 v;
    v.x = e.x + (float)a[0] + (float)b[0];
    v.y = e.y + (float)a[1] + (float)b[1];
    v.z = e.z + (float)a[2] + (float)b[2];
    v.w = e.w + (float)a[3] + (float)b[3];
    *(float4*)(out + i) = v;

    float s  = v.x + v.y + v.z + v.w;
    float s2 = v.x * v.x + v.y * v.y + v.z * v.z + v.w * v.w;
#pragma unroll
    for (int off = 1; off < 64; off <<= 1) {
        s  += __shfl_xor(s, off, 64);
        s2 += __shfl_xor(s2, off, 64);
    }
    __shared__ float red[8];
    int wid = tid >> 6;
    if ((tid & 63) == 0) { red[wid] = s; red[wid + 4] = s2; }
    __syncthreads();
    s  = red[0] + red[1] + red[2] + red[3];
    s2 = red[4] + red[5] + red[6] + red[7];
    float mu  = s * (1.0f / HIDDEN);
    float var = fmaxf(s2 * (1.0f / HIDDEN) - mu * mu, 0.0f);
    float inv = rsqrtf(var + 1e-5f);
    float4 gv = *(const float4*)(g + tid * 4);
    float4 bv = *(const float4*)(beta + tid * 4);
    bf16x4 o;
    o[0] = (__bf16)((v.x - mu) * inv * gv.x + bv.x);
    o[1] = (__bf16)((v.y - mu) * inv * gv.y + bv.y);
    o[2] = (__bf16)((v.z - mu) * inv * gv.z + bv.z);
    o[3] = (__bf16)((v.w - mu) * inv * gv.w + bv.w);
    *(bf16x4*)(h2 + i) = o;
}

// ---------------------------------------------------------------------------
// All weight converts (fp32 [K][N] -> bf16 [N][K]) in ONE launch.
// ---------------------------------------------------------------------------
__global__ __launch_bounds__(256) void convt_all(const float* __restrict__ Wq,
                                                 const float* __restrict__ Wk,
                                                 const float* __restrict__ Wv,
                                                 const float* __restrict__ Wo,
                                                 const float* __restrict__ W1,
                                                 const float* __restrict__ W2,
                                                 __bf16* __restrict__ BtQKV,
                                                 __bf16* __restrict__ BtO,
                                                 __bf16* __restrict__ Bt1,
                                                 __bf16* __restrict__ Bt2) {
    __shared__ float t[32][33];
    int id = blockIdx.x;
    const float* in; __bf16* out; int K, N, nt, kt;
    if (id < 4096) {
        int job = id >> 10, tt = id & 1023;
        nt = tt & 31; kt = tt >> 5; K = 1024; N = 1024;
        if (job == 0)      { in = Wq; out = BtQKV; }
        else if (job == 1) { in = Wk; out = BtQKV + 1024 * 1024; }
        else if (job == 2) { in = Wv; out = BtQKV + 2 * 1024 * 1024; }
        else               { in = Wo; out = BtO; }
    } else if (id < 8192) {
        int tt = id - 4096;
        nt = tt & 127; kt = tt >> 7; K = 1024; N = 4096; in = W1; out = Bt1;
    } else {
        int tt = id - 8192;
        nt = tt & 31; kt = tt >> 5; K = 4096; N = 1024; in = W2; out = Bt2;
    }
    int n0 = nt * 32, k0 = kt * 32;
    int r  = threadIdx.x >> 3;
    int c4 = (threadIdx.x & 7) * 4;
    float4 v = *(const float4*)(in + (size_t)(k0 + r) * N + n0 + c4);
    t[r][c4 + 0] = v.x; t[r][c4 + 1] = v.y; t[r][c4 + 2] = v.z; t[r][c4 + 3] = v.w;
    __syncthreads();
    bf16x4 o;
    o[0] = (__bf16)t[c4 + 0][r];
    o[1] = (__bf16)t[c4 + 1][r];
    o[2] = (__bf16)t[c4 + 2][r];
    o[3] = (__bf16)t[c4 + 3][r];
    *(bf16x4*)(out + (size_t)(n0 + r) * K + k0 + c4) = o;
}

// ---------------------------------------------------------------------------
// Shared MFMA core, 32x32x16 variant. Wave tile 64x64 = 2x2 of 32x32.
// acc reg->row: row = (reg&3) + 8*(reg>>2) + 4*(lane>>5); col = lane&31.
// ---------------------------------------------------------------------------
__device__ __forceinline__ void mfma_core128(const __bf16* __restrict__ A,
                                             const __bf16* __restrict__ Bt,
                                             int Kstride, int Klen,
                                             int m0, int n0, int tid,
                                             floatx16 (&acc)[2][2]) {
    __shared__ __bf16 As[128 * 32];
    __shared__ __bf16 Bs[128 * 32];
    int lane = tid & 63;
    int wave = tid >> 6;
    int wr = wave >> 1, wc = wave & 1;

    int sr = lane >> 2;
    int sk = (lane & 3) * 8;
    const __bf16* ga0 = A  + (size_t)(m0 + wave * 16 + sr) * Kstride + sk;
    const __bf16* ga1 = ga0 + (size_t)64 * Kstride;
    const __bf16* gb0 = Bt + (size_t)(n0 + wave * 16 + sr) * Kstride + sk;
    const __bf16* gb1 = gb0 + (size_t)64 * Kstride;
    __bf16* la0 = &As[wave * 512];
    __bf16* la1 = &As[2048 + wave * 512];
    __bf16* lb0 = &Bs[wave * 512];
    __bf16* lb1 = &Bs[2048 + wave * 512];

    int fm = lane & 31;            // row within 32x32 tile
    int fk = (lane >> 5) * 8;      // k-seg (2 halves of 8)

    for (int k0 = 0; k0 < Klen; k0 += 32) {
        __builtin_amdgcn_global_load_lds(AS1(ga0 + k0), AS3(la0), 16, 0, 0);
        __builtin_amdgcn_global_load_lds(AS1(ga1 + k0), AS3(la1), 16, 0, 0);
        __builtin_amdgcn_global_load_lds(AS1(gb0 + k0), AS3(lb0), 16, 0, 0);
        __builtin_amdgcn_global_load_lds(AS1(gb1 + k0), AS3(lb1), 16, 0, 0);
        __syncthreads();

        bf16x8 af[2][2], bfv[2][2];
#pragma unroll
        for (int i = 0; i < 2; i++)
#pragma unroll
            for (int t = 0; t < 2; t++)
                af[i][t] = *(const bf16x8*)(As + (size_t)(wr * 64 + i * 32 + fm) * 32
                                            + fk + t * 16);
#pragma unroll
        for (int j = 0; j < 2; j++)
#pragma unroll
            for (int t = 0; t < 2; t++)
                bfv[j][t] = *(const bf16x8*)(Bs + (size_t)(wc * 64 + j * 32 + fm) * 32
                                             + fk + t * 16);
#pragma unroll
        for (int t = 0; t < 2; t++)
#pragma unroll
            for (int i = 0; i < 2; i++)
#pragma unroll
                for (int j = 0; j < 2; j++)
                    acc[i][j] = __builtin_amdgcn_mfma_f32_32x32x16_bf16(
                        af[i][t], bfv[j][t], acc[i][j], 0, 0, 0);
        __syncthreads();
    }
}

// ---------------------------------------------------------------------------
// Full-K GEMM with epilogue. Grid: x indexes M (XCD L2 locality), y indexes N.
// ---------------------------------------------------------------------------
template <typename OutT, bool BIAS, bool RELU, bool RES>
__global__ __launch_bounds__(256) void mgemm(const __bf16* __restrict__ A,
                                             const __bf16* __restrict__ Bt,
                                             const float* __restrict__ bias,
                                             const float* __restrict__ res,
                                             OutT* __restrict__ C,
                                             int M, int N, int Kstride, int Klen) {
    int tid = threadIdx.x;
    int lane = tid & 63;
    int wave = tid >> 6;
    int m0 = blockIdx.x * 128, n0 = blockIdx.y * 128;
    int wr = wave >> 1, wc = wave & 1;
    floatx16 acc[2][2] = {};
    mfma_core128(A, Bt, Kstride, Klen, m0, n0, tid, acc);

#pragma unroll
    for (int i = 0; i < 2; i++) {
#pragma unroll
        for (int j = 0; j < 2; j++) {
            int col  = n0 + wc * 64 + j * 32 + (lane & 31);
            int rowb = m0 + wr * 64 + i * 32 + 4 * (lane >> 5);
#pragma unroll
            for (int reg = 0; reg < 16; reg++) {
                int row = rowb + (reg & 3) + 8 * (reg >> 2);
                float v = acc[i][j][reg];
                if (BIAS) v += bias[col];
                if (RELU) v = fmaxf(v, 0.0f);
                if (RES)  v += res[(size_t)row * N + col];
                C[(size_t)row * N + col] = (OutT)v;
            }
        }
    }
}

// ---------------------------------------------------------------------------
// Split-K GEMM: blockIdx.z picks K-chunk; writes bf16 partial tile.
// ---------------------------------------------------------------------------
__global__ __launch_bounds__(256) void mgemm_sk(const __bf16* __restrict__ A,
                                                const __bf16* __restrict__ Bt,
                                                __bf16* __restrict__ P0,
                                                __bf16* __restrict__ P3,
                                                int M, int N, int Kstride, int Klen) {
    int z = blockIdx.z;
    const __bf16* Az  = A  + (size_t)z * Klen;
    const __bf16* Btz = Bt + (size_t)z * Klen;
    __bf16* C = (z == 3) ? P3 : (P0 + (size_t)z * M * N);

    int tid = threadIdx.x;
    int lane = tid & 63;
    int wave = tid >> 6;
    int m0 = blockIdx.x * 128, n0 = blockIdx.y * 128;
    int wr = wave >> 1, wc = wave & 1;
    floatx16 acc[2][2] = {};
    mfma_core128(Az, Btz, Kstride, Klen, m0, n0, tid, acc);

#pragma unroll
    for (int i = 0; i < 2; i++) {
#pragma unroll
        for (int j = 0; j < 2; j++) {
            int col  = n0 + wc * 64 + j * 32 + (lane & 31);
            int rowb = m0 + wr * 64 + i * 32 + 4 * (lane >> 5);
#pragma unroll
            for (int reg = 0; reg < 16; reg++) {
                int row = rowb + (reg & 3) + 8 * (reg >> 2);
                C[(size_t)row * N + col] = (__bf16)acc[i][j][reg];
            }
        }
    }
}

// ---------------------------------------------------------------------------
// W2 reduction: out += p0+p1+p2+p3 + b2[col]  (in-place on out)
// ---------------------------------------------------------------------------
__global__ __launch_bounds__(256) void red_w2(const __bf16* __restrict__ p0,
                                              const __bf16* __restrict__ p3,
                                              const float* __restrict__ b2,
                                              float* __restrict__ out,
                                              int N) {
    size_t i = ((size_t)blockIdx.x * 256 + threadIdx.x) * 8;
    const size_t MN = (size_t)ROWS * HIDDEN;
    bf16x8 a = *(const bf16x8*)(p0 + i);
    bf16x8 b = *(const bf16x8*)(p0 + MN + i);
    bf16x8 c = *(const bf16x8*)(p0 + 2 * MN + i);
    bf16x8 d = *(const bf16x8*)(p3 + i);
    int col = (int)(i & (size_t)(N - 1));
    float4 bb0 = *(const float4*)(b2 + col);
    float4 bb1 = *(const float4*)(b2 + col + 4);
    float4 o0 = *(const float4*)(out + i);
    float4 o1 = *(const float4*)(out + i + 4);
    o0.x += (float)a[0] + (float)b[0] + (float)c[0] + (float)d[0] + bb0.x;
    o0.y += (float)a[1] + (float)b[1] + (float)c[1] + (float)d[1] + bb0.y;
    o0.z += (float)a[2] + (float)b[2] + (float)c[2] + (float)d[2] + bb0.z;
    o0.w += (float)a[3] + (float)b[3] + (float)c[3] + (float)d[3] + bb0.w;
    o1.x += (float)a[4] + (float)b[4] + (float)c[4] + (float)d[4] + bb1.x;
    o1.y += (float)a[5] + (float)b[5] + (float)c[5] + (float)d[5] + bb1.y;
    o1.z += (float)a[6] + (float)b[6] + (float)c[6] + (float)d[6] + bb1.z;
    o1.w += (float)a[7] + (float)b[7] + (float)c[7] + (float)d[7] + bb1.w;
    *(float4*)(out + i)     = o0;
    *(float4*)(out + i + 4) = o1;
}

// ---------------------------------------------------------------------------
// V transpose: qkv v-part [B*T][3H] -> Vt[bh][d][T]   (64x64 LDS tiles)
// ---------------------------------------------------------------------------
__global__ __launch_bounds__(256) void vtrans(const __bf16* __restrict__ qkv,
                                              __bf16* __restrict__ Vt) {
    __shared__ __bf16 t[64 * 64];
    int bh = blockIdx.x, b = bh >> 4, h = bh & 15;
    int t0 = blockIdx.y * 64;
    int tid = threadIdx.x;
    int lt = tid >> 2;
    int ds = (tid & 3) * 16;
    const __bf16* vp = qkv + (size_t)(b * SEQ + t0 + lt) * (3 * HIDDEN)
                     + 2 * HIDDEN + h * HDIM + ds;
    bf16x8 a = *(const bf16x8*)vp;
    bf16x8 c = *(const bf16x8*)(vp + 8);
#pragma unroll
    for (int i = 0; i < 8; i++) {
        int d0 = ds + i, d1 = ds + 8 + i;
        t[d0 * 64 + SWZ(d0, lt >> 3) + (lt & 7)] = a[i];
        t[d1 * 64 + SWZ(d1, lt >> 3) + (lt & 7)] = c[i];
    }
    __syncthreads();
    int dr = tid >> 2;
    int c2 = (tid & 3) * 2;
    bf16x8 o0 = *(const bf16x8*)&t[dr * 64 + SWZ(dr, c2)];
    bf16x8 o1 = *(const bf16x8*)&t[dr * 64 + SWZ(dr, c2 + 1)];
    __bf16* op = Vt + ((size_t)bh * HDIM + dr) * SEQ + t0;
    *(bf16x8*)(op + c2 * 8)     = o0;
    *(bf16x8*)(op + c2 * 8 + 8) = o1;
}

// ---------------------------------------------------------------------------
// MFMA flash attention v2 (verified R5): no-max softmax, exp2, ones-MFMA l.
// ---------------------------------------------------------------------------
__global__ __launch_bounds__(256) void attn_mfma(const __bf16* __restrict__ qkv,
                                                 const __bf16* __restrict__ Vt,
                                                 __bf16* __restrict__ ctx) {
    __shared__ __bf16 Ks[64 * 64];
    __shared__ __bf16 Vs[64 * 64];
    __shared__ __bf16 Ps[4][16 * 64];
    const int QKVW = 3 * HIDDEN;

    int bh = blockIdx.x;
    int qt = gridDim.y - 1 - blockIdx.y;
    int b = bh >> 4, h = bh & 15;
    int tid = threadIdx.x;
    int lane = tid & 63;
    int w = tid >> 6;
    int m = lane & 15;
    int g = lane >> 4;

    const float QSC = 1.44269504f / 8.0f;
    bf16x8 qf[2];
    {
        const __bf16* Qp = qkv + (size_t)(b * SEQ + qt * 64 + w * 16 + m) * QKVW
                         + h * HDIM + g * 8;
        qf[0] = *(const bf16x8*)(Qp);
        qf[1] = *(const bf16x8*)(Qp + 32);
#pragma unroll
        for (int t = 0; t < 2; t++)
#pragma unroll
            for (int i = 0; i < 8; i++)
                qf[t][i] = (__bf16)((float)qf[t][i] * QSC);
    }

    bf16x8 onesf;
#pragma unroll
    for (int i = 0; i < 8; i++) onesf[i] = (__bf16)1.0f;

    floatx4 oacc[4] = {};
    floatx4 lacc = {};

    int srow = tid >> 2;
    int sc0  = (tid & 3) * 2;
    const __bf16* Kg = qkv + (size_t)(b * SEQ) * QKVW + HIDDEN + h * HDIM;
    const __bf16* Vg = Vt + (size_t)bh * HDIM * SEQ;

    for (int kt = 0; kt <= qt; kt++) {
        __syncthreads();
        {
            const __bf16* kp = Kg + (size_t)(kt * 64 + srow) * QKVW + sc0 * 8;
            bf16x8 k0 = *(const bf16x8*)kp;
            bf16x8 k1 = *(const bf16x8*)(kp + 8);
            const __bf16* vp = Vg + (size_t)srow * SEQ + kt * 64 + sc0 * 8;
            bf16x8 v0 = *(const bf16x8*)vp;
            bf16x8 v1 = *(const bf16x8*)(vp + 8);
            *(bf16x8*)&Ks[srow * 64 + SWZ(srow, sc0)]     = k0;
            *(bf16x8*)&Ks[srow * 64 + SWZ(srow, sc0 + 1)] = k1;
            *(bf16x8*)&Vs[srow * 64 + SWZ(srow, sc0)]     = v0;
            *(bf16x8*)&Vs[srow * 64 + SWZ(srow, sc0 + 1)] = v1;
        }
        __syncthreads();

        floatx4 sacc[4] = {};
#pragma unroll
        for (int j = 0; j < 4; j++) {
#pragma unroll
            for (int t = 0; t < 2; t++) {
                int kr = 16 * j + m;
                bf16x8 kf = *(const bf16x8*)&Ks[kr * 64 + SWZ(kr, g + 4 * t)];
                sacc[j] = __builtin_amdgcn_mfma_f32_16x16x32_bf16(
                    qf[t], kf, sacc[j], 0, 0, 0);
            }
        }

        if (kt == qt) {
            int qlocal = w * 16 + 4 * g;
#pragma unroll
            for (int j = 0; j < 4; j++)
#pragma unroll
                for (int r = 0; r < 4; r++)
                    if (16 * j + m > qlocal + r) sacc[j][r] = -INFINITY;
        }

        __bf16* Pw = &Ps[w][0];
#pragma unroll
        for (int j = 0; j < 4; j++)
#pragma unroll
            for (int r = 0; r < 4; r++) {
                float p = exp2f(sacc[j][r]);
                int row = 4 * g + r;
                int key = 16 * j + m;
                Pw[row * 64 + SWZ(row, key >> 3) + (key & 7)] = (__bf16)p;
            }

#pragma unroll
        for (int t = 0; t < 2; t++) {
            bf16x8 pf = *(const bf16x8*)&Pw[m * 64 + SWZ(m, g + 4 * t)];
            lacc = __builtin_amdgcn_mfma_f32_16x16x32_bf16(pf, onesf, lacc, 0, 0, 0);
#pragma unroll
            for (int jd = 0; jd < 4; jd++) {
                int vr = 16 * jd + m;
                bf16x8 vf = *(const bf16x8*)&Vs[vr * 64 + SWZ(vr, g + 4 * t)];
                oacc[jd] = __builtin_amdgcn_mfma_f32_16x16x32_bf16(
                    pf, vf, oacc[jd], 0, 0, 0);
            }
        }
    }

#pragma unroll
    for (int r = 0; r < 4; r++) {
        float invl = 1.0f / lacc[r];
        int row = qt * 64 + w * 16 + 4 * g + r;
        __bf16* cp = ctx + (size_t)(b * SEQ + row) * HIDDEN + h * HDIM;
#pragma unroll
        for (int jd = 0; jd < 4; jd++)
            cp[16 * jd + m] = (__bf16)(oacc[jd][r] * invl);
    }
}

// ---------------------------------------------------------------------------
extern "C" void kernel_launch(void* const* d_in, const int* in_sizes, int n_in,
                              void* d_out, int out_size, void* d_ws, size_t ws_size,
                              hipStream_t stream) {
    (void)in_sizes; (void)n_in; (void)out_size; (void)ws_size;
    const float* emb = (const float*)d_in[0];
    const float* Wq  = (const float*)d_in[1];
    const float* Wk  = (const float*)d_in[2];
    const float* Wv  = (const float*)d_in[3];
    const float* Wo  = (const float*)d_in[4];
    const float* W1  = (const float*)d_in[5];
    const float* b1  = (const float*)d_in[6];
    const float* W2  = (const float*)d_in[7];
    const float* b2  = (const float*)d_in[8];
    const float* g1  = (const float*)d_in[9];
    const float* be1 = (const float*)d_in[10];
    const float* g2  = (const float*)d_in[11];
    const float* be2 = (const float*)d_in[12];
    float* out = (float*)d_out;

    // ws layout (bf16 elems; ME = 1M elems = 2MB). Total 36 ME = 72 MB.
    //   [0,4)   h (LN1) -> ctx (attn out) -> ff1 head
    //   [4,16)  qkv (dead after attn) -> Wo partials [4,12)
    //   [0,16)  ff1 (after red_wo_ln)
    //   [16,20) h2 (dead after W1 gemm) -> W2 partial z0
    //   [20,24) BtQKV+BtO -> W2 partials z1 (after their gemms)
    //   [24,28) Bt1 -> W2 partial z2
    //   [28,32) Bt2 (alive through W2 gemm)
    //   [32,36) Vt (dead after attn) -> W2 partial z3
    __bf16* wsb = (__bf16*)d_ws;
    const size_t ME = 1024 * 1024;
    __bf16* h     = wsb;
    __bf16* qkv   = wsb + 4 * ME;
    __bf16* ctx   = wsb;
    __bf16* ff1   = wsb;
    __bf16* h2    = wsb + 16 * ME;
    __bf16* BtQKV = wsb + 20 * ME;
    __bf16* BtO   = wsb + 23 * ME;
    __bf16* Bt1   = wsb + 24 * ME;
    __bf16* Bt2   = wsb + 28 * ME;
    __bf16* Vt    = wsb + 32 * ME;
    __bf16* woP   = wsb + 4 * ME;    // 2 x 4 ME
    __bf16* w2P0  = wsb + 16 * ME;   // z0..z2 contiguous (12 ME)
    __bf16* w2P3  = wsb + 32 * ME;   // z3

    convt_all<<<12288, 256, 0, stream>>>(Wq, Wk, Wv, Wo, W1, W2,
                                         BtQKV, BtO, Bt1, Bt2);

    ln_kernel<<<ROWS, 256, 0, stream>>>(emb, g1, be1, h);

    // grids: x = M/128 (XCD L2 locality), y = N/128
    mgemm<__bf16, false, false, false><<<dim3(32, 24), 256, 0, stream>>>(
        h, BtQKV, nullptr, nullptr, qkv, ROWS, 3072, 1024, 1024);

    vtrans<<<dim3(32, 32), 256, 0, stream>>>(qkv, Vt);

    attn_mfma<<<dim3(32, 32), 256, 0, stream>>>(qkv, Vt, ctx);

    // Wo split-K x2
    mgemm_sk<<<dim3(32, 8, 2), 256, 0, stream>>>(
        ctx, BtO, woP, nullptr, ROWS, 1024, 1024, 512);
    red_wo_ln<<<ROWS, 256, 0, stream>>>(emb, woP, woP + 4 * ME, g2, be2, out, h2);

    mgemm<__bf16, true, true, false><<<dim3(32, 32), 256, 0, stream>>>(
        h2, Bt1, b1, nullptr, ff1, ROWS, 4096, 1024, 1024);

    // W2 split-K x4
    mgemm_sk<<<dim3(32, 8, 4), 256, 0, stream>>>(
        ff1, Bt2, w2P0, w2P3, ROWS, 1024, 4096, 1024);
    red_w2<<<2048, 256, 0, stream>>>(w2P0, w2P3, b2, out, 1024);
}

// Round 7
// 357.186 us; speedup vs baseline: 5.3763x; 1.0137x over previous
//
#include <hip/hip_runtime.h>
#include <math.h>

#define HIDDEN 1024
#define SEQ    2048
#define NHEAD  16
#define HDIM   64
#define ROWS   (2 * SEQ)

typedef float  floatx4  __attribute__((ext_vector_type(4)));
typedef float  floatx16 __attribute__((ext_vector_type(16)));
typedef __bf16 bf16x8   __attribute__((ext_vector_type(8)));
typedef __bf16 bf16x4   __attribute__((ext_vector_type(4)));

#define AS1(p) ((const __attribute__((address_space(1))) void*)(p))
#define AS3(p) ((__attribute__((address_space(3))) void*)(p))

// swizzled byte-chunk offset (in elements): 16B chunks XOR'd by row&7
#define SWZ(row, chunk) ((((chunk) ^ ((row) & 7)) * 8))

// ---------------------------------------------------------------------------
// LayerNorm: fp32 in -> bf16 out. One block per row, 256 threads x 4 elems.
// ---------------------------------------------------------------------------
__global__ __launch_bounds__(256) void ln_kernel(const float* __restrict__ x,
                                                 const float* __restrict__ g,
                                                 const float* __restrict__ beta,
                                                 __bf16* __restrict__ out) {
    int row = blockIdx.x;
    int tid = threadIdx.x;
    const float* xr = x + (size_t)row * HIDDEN;
    float4 v = *(const float4*)(xr + tid * 4);
    float s  = v.x + v.y + v.z + v.w;
    float s2 = v.x * v.x + v.y * v.y + v.z * v.z + v.w * v.w;
#pragma unroll
    for (int off = 1; off < 64; off <<= 1) {
        s  += __shfl_xor(s, off, 64);
        s2 += __shfl_xor(s2, off, 64);
    }
    __shared__ float red[8];
    int wid = tid >> 6;
    if ((tid & 63) == 0) { red[wid] = s; red[wid + 4] = s2; }
    __syncthreads();
    s  = red[0] + red[1] + red[2] + red[3];
    s2 = red[4] + red[5] + red[6] + red[7];
    float mu  = s * (1.0f / HIDDEN);
    float var = fmaxf(s2 * (1.0f / HIDDEN) - mu * mu, 0.0f);
    float inv = rsqrtf(var + 1e-5f);
    float4 gv = *(const float4*)(g + tid * 4);
    float4 bv = *(const float4*)(beta + tid * 4);
    bf16x4 o;
    o[0] = (__bf16)((v.x - mu) * inv * gv.x + bv.x);
    o[1] = (__bf16)((v.y - mu) * inv * gv.y + bv.y);
    o[2] = (__bf16)((v.z - mu) * inv * gv.z + bv.z);
    o[3] = (__bf16)((v.w - mu) * inv * gv.w + bv.w);
    *(bf16x4*)(out + (size_t)row * HIDDEN + tid * 4) = o;
}

// ---------------------------------------------------------------------------
// Fused Wo-split-K reduction + residual + LayerNorm2.
// ---------------------------------------------------------------------------
__global__ __launch_bounds__(256) void red_wo_ln(const float* __restrict__ emb,
                                                 const __bf16* __restrict__ p0,
                                                 const __bf16* __restrict__ p1,
                                                 const float* __restrict__ g,
                                                 const float* __restrict__ beta,
                                                 float* __restrict__ out,
                                                 __bf16* __restrict__ h2) {
    int row = blockIdx.x;
    int tid = threadIdx.x;
    size_t i = (size_t)row * HIDDEN + tid * 4;
    float4 e = *(const float4*)(emb + i);
    bf16x4 a = *(const bf16x4*)(p0 + i);
    bf16x4 b = *(const bf16x4*)(p1 + i);
    float4 v;
    v.x = e.x + (float)a[0] + (float)b[0];
    v.y = e.y + (float)a[1] + (float)b[1];
    v.z = e.z + (float)a[2] + (float)b[2];
    v.w = e.w + (float)a[3] + (float)b[3];
    *(float4*)(out + i) = v;

    float s  = v.x + v.y + v.z + v.w;
    float s2 = v.x * v.x + v.y * v.y + v.z * v.z + v.w * v.w;
#pragma unroll
    for (int off = 1; off < 64; off <<= 1) {
        s  += __shfl_xor(s, off, 64);
        s2 += __shfl_xor(s2, off, 64);
    }
    __shared__ float red[8];
    int wid = tid >> 6;
    if ((tid & 63) == 0) { red[wid] = s; red[wid + 4] = s2; }
    __syncthreads();
    s  = red[0] + red[1] + red[2] + red[3];
    s2 = red[4] + red[5] + red[6] + red[7];
    float mu  = s * (1.0f / HIDDEN);
    float var = fmaxf(s2 * (1.0f / HIDDEN) - mu * mu, 0.0f);
    float inv = rsqrtf(var + 1e-5f);
    float4 gv = *(const float4*)(g + tid * 4);
    float4 bv = *(const float4*)(beta + tid * 4);
    bf16x4 o;
    o[0] = (__bf16)((v.x - mu) * inv * gv.x + bv.x);
    o[1] = (__bf16)((v.y - mu) * inv * gv.y + bv.y);
    o[2] = (__bf16)((v.z - mu) * inv * gv.z + bv.z);
    o[3] = (__bf16)((v.w - mu) * inv * gv.w + bv.w);
    *(bf16x4*)(h2 + i) = o;
}

// ---------------------------------------------------------------------------
// All weight converts (fp32 [K][N] -> bf16 [N][K]) in ONE launch.
// ---------------------------------------------------------------------------
__global__ __launch_bounds__(256) void convt_all(const float* __restrict__ Wq,
                                                 const float* __restrict__ Wk,
                                                 const float* __restrict__ Wv,
                                                 const float* __restrict__ Wo,
                                                 const float* __restrict__ W1,
                                                 const float* __restrict__ W2,
                                                 __bf16* __restrict__ BtQKV,
                                                 __bf16* __restrict__ BtO,
                                                 __bf16* __restrict__ Bt1,
                                                 __bf16* __restrict__ Bt2) {
    __shared__ float t[32][33];
    int id = blockIdx.x;
    const float* in; __bf16* out; int K, N, nt, kt;
    if (id < 4096) {
        int job = id >> 10, tt = id & 1023;
        nt = tt & 31; kt = tt >> 5; K = 1024; N = 1024;
        if (job == 0)      { in = Wq; out = BtQKV; }
        else if (job == 1) { in = Wk; out = BtQKV + 1024 * 1024; }
        else if (job == 2) { in = Wv; out = BtQKV + 2 * 1024 * 1024; }
        else               { in = Wo; out = BtO; }
    } else if (id < 8192) {
        int tt = id - 4096;
        nt = tt & 127; kt = tt >> 7; K = 1024; N = 4096; in = W1; out = Bt1;
    } else {
        int tt = id - 8192;
        nt = tt & 31; kt = tt >> 5; K = 4096; N = 1024; in = W2; out = Bt2;
    }
    int n0 = nt * 32, k0 = kt * 32;
    int r  = threadIdx.x >> 3;
    int c4 = (threadIdx.x & 7) * 4;
    float4 v = *(const float4*)(in + (size_t)(k0 + r) * N + n0 + c4);
    t[r][c4 + 0] = v.x; t[r][c4 + 1] = v.y; t[r][c4 + 2] = v.z; t[r][c4 + 3] = v.w;
    __syncthreads();
    bf16x4 o;
    o[0] = (__bf16)t[c4 + 0][r];
    o[1] = (__bf16)t[c4 + 1][r];
    o[2] = (__bf16)t[c4 + 2][r];
    o[3] = (__bf16)t[c4 + 3][r];
    *(bf16x4*)(out + (size_t)(n0 + r) * K + k0 + c4) = o;
}

// ---------------------------------------------------------------------------
// Shared MFMA core, 32x32x16, XOR-swizzled LDS.
// Logical chunk c (16B) of row r lives at physical slot c ^ ((r>>1)&3):
// staging lane 4*r_loc+slot fetches global chunk slot^((r_loc>>1)&3); reads
// compute slot = chunk ^ ((row>>1)&3). Bank-group = 4*(row&1) + slot covers
// all 8 groups exactly 8 lanes each -> minimal b128 aliasing.
// ---------------------------------------------------------------------------
__device__ __forceinline__ void mfma_core128(const __bf16* __restrict__ A,
                                             const __bf16* __restrict__ Bt,
                                             int Kstride, int Klen,
                                             int m0, int n0, int tid,
                                             floatx16 (&acc)[2][2]) {
    __shared__ __bf16 As[128 * 32];
    __shared__ __bf16 Bs[128 * 32];
    int lane = tid & 63;
    int wave = tid >> 6;
    int wr = wave >> 1, wc = wave & 1;

    int sr = lane >> 2;                                // row within 16
    int sk = 8 * ((lane & 3) ^ ((sr >> 1) & 3));       // swizzled global chunk
    const __bf16* ga0 = A  + (size_t)(m0 + wave * 16 + sr) * Kstride + sk;
    const __bf16* ga1 = ga0 + (size_t)64 * Kstride;
    const __bf16* gb0 = Bt + (size_t)(n0 + wave * 16 + sr) * Kstride + sk;
    const __bf16* gb1 = gb0 + (size_t)64 * Kstride;
    __bf16* la0 = &As[wave * 512];
    __bf16* la1 = &As[2048 + wave * 512];
    __bf16* lb0 = &Bs[wave * 512];
    __bf16* lb1 = &Bs[2048 + wave * 512];

    int fm = lane & 31;                    // row within 32x32 tile
    int gswz = (lane >> 1) & 3;            // (row>>1)&3
    int slot0 = ((lane >> 5) + 0) ^ gswz;  // t=0: logical chunk (lane>>5)
    int slot1 = ((lane >> 5) + 2) ^ gswz;  // t=1: logical chunk (lane>>5)+2

    for (int k0 = 0; k0 < Klen; k0 += 32) {
        __builtin_amdgcn_global_load_lds(AS1(ga0 + k0), AS3(la0), 16, 0, 0);
        __builtin_amdgcn_global_load_lds(AS1(ga1 + k0), AS3(la1), 16, 0, 0);
        __builtin_amdgcn_global_load_lds(AS1(gb0 + k0), AS3(lb0), 16, 0, 0);
        __builtin_amdgcn_global_load_lds(AS1(gb1 + k0), AS3(lb1), 16, 0, 0);
        __syncthreads();

        bf16x8 af[2][2], bfv[2][2];
#pragma unroll
        for (int i = 0; i < 2; i++) {
            const __bf16* rp = As + (size_t)(wr * 64 + i * 32 + fm) * 32;
            af[i][0] = *(const bf16x8*)(rp + slot0 * 8);
            af[i][1] = *(const bf16x8*)(rp + slot1 * 8);
        }
#pragma unroll
        for (int j = 0; j < 2; j++) {
            const __bf16* rp = Bs + (size_t)(wc * 64 + j * 32 + fm) * 32;
            bfv[j][0] = *(const bf16x8*)(rp + slot0 * 8);
            bfv[j][1] = *(const bf16x8*)(rp + slot1 * 8);
        }
#pragma unroll
        for (int t = 0; t < 2; t++)
#pragma unroll
            for (int i = 0; i < 2; i++)
#pragma unroll
                for (int j = 0; j < 2; j++)
                    acc[i][j] = __builtin_amdgcn_mfma_f32_32x32x16_bf16(
                        af[i][t], bfv[j][t], acc[i][j], 0, 0, 0);
        __syncthreads();
    }
}

// ---------------------------------------------------------------------------
// Full-K GEMM with epilogue. Grid: x indexes M (XCD L2 locality), y indexes N.
// ---------------------------------------------------------------------------
template <typename OutT, bool BIAS, bool RELU, bool RES>
__global__ __launch_bounds__(256) void mgemm(const __bf16* __restrict__ A,
                                             const __bf16* __restrict__ Bt,
                                             const float* __restrict__ bias,
                                             const float* __restrict__ res,
                                             OutT* __restrict__ C,
                                             int M, int N, int Kstride, int Klen) {
    int tid = threadIdx.x;
    int lane = tid & 63;
    int wave = tid >> 6;
    int m0 = blockIdx.x * 128, n0 = blockIdx.y * 128;
    int wr = wave >> 1, wc = wave & 1;
    floatx16 acc[2][2] = {};
    mfma_core128(A, Bt, Kstride, Klen, m0, n0, tid, acc);

#pragma unroll
    for (int i = 0; i < 2; i++) {
#pragma unroll
        for (int j = 0; j < 2; j++) {
            int col  = n0 + wc * 64 + j * 32 + (lane & 31);
            int rowb = m0 + wr * 64 + i * 32 + 4 * (lane >> 5);
#pragma unroll
            for (int reg = 0; reg < 16; reg++) {
                int row = rowb + (reg & 3) + 8 * (reg >> 2);
                float v = acc[i][j][reg];
                if (BIAS) v += bias[col];
                if (RELU) v = fmaxf(v, 0.0f);
                if (RES)  v += res[(size_t)row * N + col];
                C[(size_t)row * N + col] = (OutT)v;
            }
        }
    }
}

// ---------------------------------------------------------------------------
// Split-K GEMM: blockIdx.z picks K-chunk; writes bf16 partial tile.
// ---------------------------------------------------------------------------
__global__ __launch_bounds__(256) void mgemm_sk(const __bf16* __restrict__ A,
                                                const __bf16* __restrict__ Bt,
                                                __bf16* __restrict__ P0,
                                                __bf16* __restrict__ P3,
                                                int M, int N, int Kstride, int Klen) {
    int z = blockIdx.z;
    const __bf16* Az  = A  + (size_t)z * Klen;
    const __bf16* Btz = Bt + (size_t)z * Klen;
    __bf16* C = (z == 3) ? P3 : (P0 + (size_t)z * M * N);

    int tid = threadIdx.x;
    int lane = tid & 63;
    int wave = tid >> 6;
    int m0 = blockIdx.x * 128, n0 = blockIdx.y * 128;
    int wr = wave >> 1, wc = wave & 1;
    floatx16 acc[2][2] = {};
    mfma_core128(Az, Btz, Kstride, Klen, m0, n0, tid, acc);

#pragma unroll
    for (int i = 0; i < 2; i++) {
#pragma unroll
        for (int j = 0; j < 2; j++) {
            int col  = n0 + wc * 64 + j * 32 + (lane & 31);
            int rowb = m0 + wr * 64 + i * 32 + 4 * (lane >> 5);
#pragma unroll
            for (int reg = 0; reg < 16; reg++) {
                int row = rowb + (reg & 3) + 8 * (reg >> 2);
                C[(size_t)row * N + col] = (__bf16)acc[i][j][reg];
            }
        }
    }
}

// ---------------------------------------------------------------------------
// W2 reduction: out += p0+p1+p2+p3 + b2[col]  (in-place on out)
// ---------------------------------------------------------------------------
__global__ __launch_bounds__(256) void red_w2(const __bf16* __restrict__ p0,
                                              const __bf16* __restrict__ p3,
                                              const float* __restrict__ b2,
                                              float* __restrict__ out,
                                              int N) {
    size_t i = ((size_t)blockIdx.x * 256 + threadIdx.x) * 8;
    const size_t MN = (size_t)ROWS * HIDDEN;
    bf16x8 a = *(const bf16x8*)(p0 + i);
    bf16x8 b = *(const bf16x8*)(p0 + MN + i);
    bf16x8 c = *(const bf16x8*)(p0 + 2 * MN + i);
    bf16x8 d = *(const bf16x8*)(p3 + i);
    int col = (int)(i & (size_t)(N - 1));
    float4 bb0 = *(const float4*)(b2 + col);
    float4 bb1 = *(const float4*)(b2 + col + 4);
    float4 o0 = *(const float4*)(out + i);
    float4 o1 = *(const float4*)(out + i + 4);
    o0.x += (float)a[0] + (float)b[0] + (float)c[0] + (float)d[0] + bb0.x;
    o0.y += (float)a[1] + (float)b[1] + (float)c[1] + (float)d[1] + bb0.y;
    o0.z += (float)a[2] + (float)b[2] + (float)c[2] + (float)d[2] + bb0.z;
    o0.w += (float)a[3] + (float)b[3] + (float)c[3] + (float)d[3] + bb0.w;
    o1.x += (float)a[4] + (float)b[4] + (float)c[4] + (float)d[4] + bb1.x;
    o1.y += (float)a[5] + (float)b[5] + (float)c[5] + (float)d[5] + bb1.y;
    o1.z += (float)a[6] + (float)b[6] + (float)c[6] + (float)d[6] + bb1.z;
    o1.w += (float)a[7] + (float)b[7] + (float)c[7] + (float)d[7] + bb1.w;
    *(float4*)(out + i)     = o0;
    *(float4*)(out + i + 4) = o1;
}

// ---------------------------------------------------------------------------
// V transpose: qkv v-part [B*T][3H] -> Vt[bh][d][T]   (64x64 LDS tiles)
// ---------------------------------------------------------------------------
__global__ __launch_bounds__(256) void vtrans(const __bf16* __restrict__ qkv,
                                              __bf16* __restrict__ Vt) {
    __shared__ __bf16 t[64 * 64];
    int bh = blockIdx.x, b = bh >> 4, h = bh & 15;
    int t0 = blockIdx.y * 64;
    int tid = threadIdx.x;
    int lt = tid >> 2;
    int ds = (tid & 3) * 16;
    const __bf16* vp = qkv + (size_t)(b * SEQ + t0 + lt) * (3 * HIDDEN)
                     + 2 * HIDDEN + h * HDIM + ds;
    bf16x8 a = *(const bf16x8*)vp;
    bf16x8 c = *(const bf16x8*)(vp + 8);
#pragma unroll
    for (int i = 0; i < 8; i++) {
        int d0 = ds + i, d1 = ds + 8 + i;
        t[d0 * 64 + SWZ(d0, lt >> 3) + (lt & 7)] = a[i];
        t[d1 * 64 + SWZ(d1, lt >> 3) + (lt & 7)] = c[i];
    }
    __syncthreads();
    int dr = tid >> 2;
    int c2 = (tid & 3) * 2;
    bf16x8 o0 = *(const bf16x8*)&t[dr * 64 + SWZ(dr, c2)];
    bf16x8 o1 = *(const bf16x8*)&t[dr * 64 + SWZ(dr, c2 + 1)];
    __bf16* op = Vt + ((size_t)bh * HDIM + dr) * SEQ + t0;
    *(bf16x8*)(op + c2 * 8)     = o0;
    *(bf16x8*)(op + c2 * 8 + 8) = o1;
}

// ---------------------------------------------------------------------------
// MFMA flash attention v2 (verified R5): no-max softmax, exp2, ones-MFMA l.
// ---------------------------------------------------------------------------
__global__ __launch_bounds__(256) void attn_mfma(const __bf16* __restrict__ qkv,
                                                 const __bf16* __restrict__ Vt,
                                                 __bf16* __restrict__ ctx) {
    __shared__ __bf16 Ks[64 * 64];
    __shared__ __bf16 Vs[64 * 64];
    __shared__ __bf16 Ps[4][16 * 64];
    const int QKVW = 3 * HIDDEN;

    int bh = blockIdx.x;
    int qt = gridDim.y - 1 - blockIdx.y;
    int b = bh >> 4, h = bh & 15;
    int tid = threadIdx.x;
    int lane = tid & 63;
    int w = tid >> 6;
    int m = lane & 15;
    int g = lane >> 4;

    const float QSC = 1.44269504f / 8.0f;
    bf16x8 qf[2];
    {
        const __bf16* Qp = qkv + (size_t)(b * SEQ + qt * 64 + w * 16 + m) * QKVW
                         + h * HDIM + g * 8;
        qf[0] = *(const bf16x8*)(Qp);
        qf[1] = *(const bf16x8*)(Qp + 32);
#pragma unroll
        for (int t = 0; t < 2; t++)
#pragma unroll
            for (int i = 0; i < 8; i++)
                qf[t][i] = (__bf16)((float)qf[t][i] * QSC);
    }

    bf16x8 onesf;
#pragma unroll
    for (int i = 0; i < 8; i++) onesf[i] = (__bf16)1.0f;

    floatx4 oacc[4] = {};
    floatx4 lacc = {};

    int srow = tid >> 2;
    int sc0  = (tid & 3) * 2;
    const __bf16* Kg = qkv + (size_t)(b * SEQ) * QKVW + HIDDEN + h * HDIM;
    const __bf16* Vg = Vt + (size_t)bh * HDIM * SEQ;

    for (int kt = 0; kt <= qt; kt++) {
        __syncthreads();
        {
            const __bf16* kp = Kg + (size_t)(kt * 64 + srow) * QKVW + sc0 * 8;
            bf16x8 k0 = *(const bf16x8*)kp;
            bf16x8 k1 = *(const bf16x8*)(kp + 8);
            const __bf16* vp = Vg + (size_t)srow * SEQ + kt * 64 + sc0 * 8;
            bf16x8 v0 = *(const bf16x8*)vp;
            bf16x8 v1 = *(const bf16x8*)(vp + 8);
            *(bf16x8*)&Ks[srow * 64 + SWZ(srow, sc0)]     = k0;
            *(bf16x8*)&Ks[srow * 64 + SWZ(srow, sc0 + 1)] = k1;
            *(bf16x8*)&Vs[srow * 64 + SWZ(srow, sc0)]     = v0;
            *(bf16x8*)&Vs[srow * 64 + SWZ(srow, sc0 + 1)] = v1;
        }
        __syncthreads();

        floatx4 sacc[4] = {};
#pragma unroll
        for (int j = 0; j < 4; j++) {
#pragma unroll
            for (int t = 0; t < 2; t++) {
                int kr = 16 * j + m;
                bf16x8 kf = *(const bf16x8*)&Ks[kr * 64 + SWZ(kr, g + 4 * t)];
                sacc[j] = __builtin_amdgcn_mfma_f32_16x16x32_bf16(
                    qf[t], kf, sacc[j], 0, 0, 0);
            }
        }

        if (kt == qt) {
            int qlocal = w * 16 + 4 * g;
#pragma unroll
            for (int j = 0; j < 4; j++)
#pragma unroll
                for (int r = 0; r < 4; r++)
                    if (16 * j + m > qlocal + r) sacc[j][r] = -INFINITY;
        }

        __bf16* Pw = &Ps[w][0];
#pragma unroll
        for (int j = 0; j < 4; j++)
#pragma unroll
            for (int r = 0; r < 4; r++) {
                float p = exp2f(sacc[j][r]);
                int row = 4 * g + r;
                int key = 16 * j + m;
                Pw[row * 64 + SWZ(row, key >> 3) + (key & 7)] = (__bf16)p;
            }

#pragma unroll
        for (int t = 0; t < 2; t++) {
            bf16x8 pf = *(const bf16x8*)&Pw[m * 64 + SWZ(m, g + 4 * t)];
            lacc = __builtin_amdgcn_mfma_f32_16x16x32_bf16(pf, onesf, lacc, 0, 0, 0);
#pragma unroll
            for (int jd = 0; jd < 4; jd++) {
                int vr = 16 * jd + m;
                bf16x8 vf = *(const bf16x8*)&Vs[vr * 64 + SWZ(vr, g + 4 * t)];
                oacc[jd] = __builtin_amdgcn_mfma_f32_16x16x32_bf16(
                    pf, vf, oacc[jd], 0, 0, 0);
            }
        }
    }

#pragma unroll
    for (int r = 0; r < 4; r++) {
        float invl = 1.0f / lacc[r];
        int row = qt * 64 + w * 16 + 4 * g + r;
        __bf16* cp = ctx + (size_t)(b * SEQ + row) * HIDDEN + h * HDIM;
#pragma unroll
        for (int jd = 0; jd < 4; jd++)
            cp[16 * jd + m] = (__bf16)(oacc[jd][r] * invl);
    }
}

// ---------------------------------------------------------------------------
extern "C" void kernel_launch(void* const* d_in, const int* in_sizes, int n_in,
                              void* d_out, int out_size, void* d_ws, size_t ws_size,
                              hipStream_t stream) {
    (void)in_sizes; (void)n_in; (void)out_size; (void)ws_size;
    const float* emb = (const float*)d_in[0];
    const float* Wq  = (const float*)d_in[1];
    const float* Wk  = (const float*)d_in[2];
    const float* Wv  = (const float*)d_in[3];
    const float* Wo  = (const float*)d_in[4];
    const float* W1  = (const float*)d_in[5];
    const float* b1  = (const float*)d_in[6];
    const float* W2  = (const float*)d_in[7];
    const float* b2  = (const float*)d_in[8];
    const float* g1  = (const float*)d_in[9];
    const float* be1 = (const float*)d_in[10];
    const float* g2  = (const float*)d_in[11];
    const float* be2 = (const float*)d_in[12];
    float* out = (float*)d_out;

    // ws layout (bf16 elems; ME = 1M elems = 2MB). Total 36 ME = 72 MB.
    __bf16* wsb = (__bf16*)d_ws;
    const size_t ME = 1024 * 1024;
    __bf16* h     = wsb;
    __bf16* qkv   = wsb + 4 * ME;
    __bf16* ctx   = wsb;
    __bf16* ff1   = wsb;
    __bf16* h2    = wsb + 16 * ME;
    __bf16* BtQKV = wsb + 20 * ME;
    __bf16* BtO   = wsb + 23 * ME;
    __bf16* Bt1   = wsb + 24 * ME;
    __bf16* Bt2   = wsb + 28 * ME;
    __bf16* Vt    = wsb + 32 * ME;
    __bf16* woP   = wsb + 4 * ME;    // 2 x 4 ME
    __bf16* w2P0  = wsb + 16 * ME;   // z0..z2 contiguous (12 ME)
    __bf16* w2P3  = wsb + 32 * ME;   // z3

    convt_all<<<12288, 256, 0, stream>>>(Wq, Wk, Wv, Wo, W1, W2,
                                         BtQKV, BtO, Bt1, Bt2);

    ln_kernel<<<ROWS, 256, 0, stream>>>(emb, g1, be1, h);

    // grids: x = M/128 (XCD L2 locality), y = N/128
    mgemm<__bf16, false, false, false><<<dim3(32, 24), 256, 0, stream>>>(
        h, BtQKV, nullptr, nullptr, qkv, ROWS, 3072, 1024, 1024);

    vtrans<<<dim3(32, 32), 256, 0, stream>>>(qkv, Vt);

    attn_mfma<<<dim3(32, 32), 256, 0, stream>>>(qkv, Vt, ctx);

    // Wo split-K x2
    mgemm_sk<<<dim3(32, 8, 2), 256, 0, stream>>>(
        ctx, BtO, woP, nullptr, ROWS, 1024, 1024, 512);
    red_wo_ln<<<ROWS, 256, 0, stream>>>(emb, woP, woP + 4 * ME, g2, be2, out, h2);

    mgemm<__bf16, true, true, false><<<dim3(32, 32), 256, 0, stream>>>(
        h2, Bt1, b1, nullptr, ff1, ROWS, 4096, 1024, 1024);

    // W2 split-K x4
    mgemm_sk<<<dim3(32, 8, 4), 256, 0, stream>>>(
        ff1, Bt2, w2P0, w2P3, ROWS, 1024, 4096, 1024);
    red_w2<<<2048, 256, 0, stream>>>(w2P0, w2P3, b2, out, 1024);
}

// Round 8
// 345.133 us; speedup vs baseline: 5.5640x; 1.0349x over previous
//
#include <hip/hip_runtime.h>
#include <math.h>

#define HIDDEN 1024
#define SEQ    2048
#define NHEAD  16
#define HDIM   64
#define ROWS   (2 * SEQ)

typedef float  floatx4  __attribute__((ext_vector_type(4)));
typedef float  floatx16 __attribute__((ext_vector_type(16)));
typedef __bf16 bf16x8   __attribute__((ext_vector_type(8)));
typedef __bf16 bf16x4   __attribute__((ext_vector_type(4)));

#define AS1(p) ((const __attribute__((address_space(1))) void*)(p))
#define AS3(p) ((__attribute__((address_space(3))) void*)(p))

// swizzled byte-chunk offset (in elements): 16B chunks XOR'd by row&7
#define SWZ(row, chunk) ((((chunk) ^ ((row) & 7)) * 8))

// ---------------------------------------------------------------------------
// Prep launch: 6 weight converts (fp32 [K][N] -> bf16 [N][K]) + LayerNorm1,
// all in ONE kernel. Blocks [0,12288) convt tiles; [12288,16384) LN rows.
// ---------------------------------------------------------------------------
__global__ __launch_bounds__(256) void prep_all(const float* __restrict__ Wq,
                                                const float* __restrict__ Wk,
                                                const float* __restrict__ Wv,
                                                const float* __restrict__ Wo,
                                                const float* __restrict__ W1,
                                                const float* __restrict__ W2,
                                                __bf16* __restrict__ BtQKV,
                                                __bf16* __restrict__ BtO,
                                                __bf16* __restrict__ Bt1,
                                                __bf16* __restrict__ Bt2,
                                                const float* __restrict__ emb,
                                                const float* __restrict__ g1,
                                                const float* __restrict__ be1,
                                                __bf16* __restrict__ h) {
    int id = blockIdx.x;
    int tid = threadIdx.x;
    if (id >= 12288) {
        // ---- LayerNorm1 row ----
        int row = id - 12288;
        const float* xr = emb + (size_t)row * HIDDEN;
        float4 v = *(const float4*)(xr + tid * 4);
        float s  = v.x + v.y + v.z + v.w;
        float s2 = v.x * v.x + v.y * v.y + v.z * v.z + v.w * v.w;
#pragma unroll
        for (int off = 1; off < 64; off <<= 1) {
            s  += __shfl_xor(s, off, 64);
            s2 += __shfl_xor(s2, off, 64);
        }
        __shared__ float red[8];
        int wid = tid >> 6;
        if ((tid & 63) == 0) { red[wid] = s; red[wid + 4] = s2; }
        __syncthreads();
        s  = red[0] + red[1] + red[2] + red[3];
        s2 = red[4] + red[5] + red[6] + red[7];
        float mu  = s * (1.0f / HIDDEN);
        float var = fmaxf(s2 * (1.0f / HIDDEN) - mu * mu, 0.0f);
        float inv = rsqrtf(var + 1e-5f);
        float4 gv = *(const float4*)(g1 + tid * 4);
        float4 bv = *(const float4*)(be1 + tid * 4);
        bf16x4 o;
        o[0] = (__bf16)((v.x - mu) * inv * gv.x + bv.x);
        o[1] = (__bf16)((v.y - mu) * inv * gv.y + bv.y);
        o[2] = (__bf16)((v.z - mu) * inv * gv.z + bv.z);
        o[3] = (__bf16)((v.w - mu) * inv * gv.w + bv.w);
        *(bf16x4*)(h + (size_t)row * HIDDEN + tid * 4) = o;
        return;
    }
    // ---- weight convert tile ----
    __shared__ float t[32][33];
    const float* in; __bf16* out; int K, N, nt, kt;
    if (id < 4096) {
        int job = id >> 10, tt = id & 1023;
        nt = tt & 31; kt = tt >> 5; K = 1024; N = 1024;
        if (job == 0)      { in = Wq; out = BtQKV; }
        else if (job == 1) { in = Wk; out = BtQKV + 1024 * 1024; }
        else if (job == 2) { in = Wv; out = BtQKV + 2 * 1024 * 1024; }
        else               { in = Wo; out = BtO; }
    } else if (id < 8192) {
        int tt = id - 4096;
        nt = tt & 127; kt = tt >> 7; K = 1024; N = 4096; in = W1; out = Bt1;
    } else {
        int tt = id - 8192;
        nt = tt & 31; kt = tt >> 5; K = 4096; N = 1024; in = W2; out = Bt2;
    }
    int n0 = nt * 32, k0 = kt * 32;
    int r  = tid >> 3;
    int c4 = (tid & 7) * 4;
    float4 v = *(const float4*)(in + (size_t)(k0 + r) * N + n0 + c4);
    t[r][c4 + 0] = v.x; t[r][c4 + 1] = v.y; t[r][c4 + 2] = v.z; t[r][c4 + 3] = v.w;
    __syncthreads();
    bf16x4 o;
    o[0] = (__bf16)t[c4 + 0][r];
    o[1] = (__bf16)t[c4 + 1][r];
    o[2] = (__bf16)t[c4 + 2][r];
    o[3] = (__bf16)t[c4 + 3][r];
    *(bf16x4*)(out + (size_t)(n0 + r) * K + k0 + c4) = o;
}

// ---------------------------------------------------------------------------
// Fused Wo-split-K reduction + residual + LayerNorm2.
// ---------------------------------------------------------------------------
__global__ __launch_bounds__(256) void red_wo_ln(const float* __restrict__ emb,
                                                 const __bf16* __restrict__ p0,
                                                 const __bf16* __restrict__ p1,
                                                 const float* __restrict__ g,
                                                 const float* __restrict__ beta,
                                                 float* __restrict__ out,
                                                 __bf16* __restrict__ h2) {
    int row = blockIdx.x;
    int tid = threadIdx.x;
    size_t i = (size_t)row * HIDDEN + tid * 4;
    float4 e = *(const float4*)(emb + i);
    bf16x4 a = *(const bf16x4*)(p0 + i);
    bf16x4 b = *(const bf16x4*)(p1 + i);
    float4 v;
    v.x = e.x + (float)a[0] + (float)b[0];
    v.y = e.y + (float)a[1] + (float)b[1];
    v.z = e.z + (float)a[2] + (float)b[2];
    v.w = e.w + (float)a[3] + (float)b[3];
    *(float4*)(out + i) = v;

    float s  = v.x + v.y + v.z + v.w;
    float s2 = v.x * v.x + v.y * v.y + v.z * v.z + v.w * v.w;
#pragma unroll
    for (int off = 1; off < 64; off <<= 1) {
        s  += __shfl_xor(s, off, 64);
        s2 += __shfl_xor(s2, off, 64);
    }
    __shared__ float red[8];
    int wid = tid >> 6;
    if ((tid & 63) == 0) { red[wid] = s; red[wid + 4] = s2; }
    __syncthreads();
    s  = red[0] + red[1] + red[2] + red[3];
    s2 = red[4] + red[5] + red[6] + red[7];
    float mu  = s * (1.0f / HIDDEN);
    float var = fmaxf(s2 * (1.0f / HIDDEN) - mu * mu, 0.0f);
    float inv = rsqrtf(var + 1e-5f);
    float4 gv = *(const float4*)(g + tid * 4);
    float4 bv = *(const float4*)(beta + tid * 4);
    bf16x4 o;
    o[0] = (__bf16)((v.x - mu) * inv * gv.x + bv.x);
    o[1] = (__bf16)((v.y - mu) * inv * gv.y + bv.y);
    o[2] = (__bf16)((v.z - mu) * inv * gv.z + bv.z);
    o[3] = (__bf16)((v.w - mu) * inv * gv.w + bv.w);
    *(bf16x4*)(h2 + i) = o;
}

// ---------------------------------------------------------------------------
// Shared MFMA core, 32x32x16, XOR-swizzled LDS, DOUBLE-BUFFERED staging.
// One barrier per K-iter; tile k+1's global_load_lds is issued right after
// the barrier so the next barrier's vmcnt(0) drain finds it already landed.
// ---------------------------------------------------------------------------
__device__ __forceinline__ void mfma_core128(const __bf16* __restrict__ A,
                                             const __bf16* __restrict__ Bt,
                                             int Kstride, int Klen,
                                             int m0, int n0, int tid,
                                             floatx16 (&acc)[2][2]) {
    __shared__ __bf16 As[2 * 128 * 32];
    __shared__ __bf16 Bs[2 * 128 * 32];
    const int BUF = 128 * 32;
    int lane = tid & 63;
    int wave = tid >> 6;
    int wr = wave >> 1, wc = wave & 1;

    int sr = lane >> 2;                                // row within 16
    int sk = 8 * ((lane & 3) ^ ((sr >> 1) & 3));       // swizzled global chunk
    const __bf16* ga0 = A  + (size_t)(m0 + wave * 16 + sr) * Kstride + sk;
    const __bf16* ga1 = ga0 + (size_t)64 * Kstride;
    const __bf16* gb0 = Bt + (size_t)(n0 + wave * 16 + sr) * Kstride + sk;
    const __bf16* gb1 = gb0 + (size_t)64 * Kstride;
    __bf16* la0 = &As[wave * 512];
    __bf16* la1 = &As[2048 + wave * 512];
    __bf16* lb0 = &Bs[wave * 512];
    __bf16* lb1 = &Bs[2048 + wave * 512];

    int fm = lane & 31;                    // row within 32x32 tile
    int gswz = (lane >> 1) & 3;
    int slot0 = ((lane >> 5) + 0) ^ gswz;
    int slot1 = ((lane >> 5) + 2) ^ gswz;

    // preload tile 0 into buffer 0
    __builtin_amdgcn_global_load_lds(AS1(ga0), AS3(la0), 16, 0, 0);
    __builtin_amdgcn_global_load_lds(AS1(ga1), AS3(la1), 16, 0, 0);
    __builtin_amdgcn_global_load_lds(AS1(gb0), AS3(lb0), 16, 0, 0);
    __builtin_amdgcn_global_load_lds(AS1(gb1), AS3(lb1), 16, 0, 0);

    int buf = 0;
    for (int k0 = 0; k0 < Klen; k0 += 32, buf ^= 1) {
        __syncthreads();   // staging of buf landed; prev reads of buf^1 done
        if (k0 + 32 < Klen) {
            int nb = (buf ^ 1) * BUF;
            __builtin_amdgcn_global_load_lds(AS1(ga0 + k0 + 32), AS3(la0 + nb), 16, 0, 0);
            __builtin_amdgcn_global_load_lds(AS1(ga1 + k0 + 32), AS3(la1 + nb), 16, 0, 0);
            __builtin_amdgcn_global_load_lds(AS1(gb0 + k0 + 32), AS3(lb0 + nb), 16, 0, 0);
            __builtin_amdgcn_global_load_lds(AS1(gb1 + k0 + 32), AS3(lb1 + nb), 16, 0, 0);
        }
        const __bf16* Ab = As + buf * BUF;
        const __bf16* Bb = Bs + buf * BUF;

        bf16x8 af[2][2], bfv[2][2];
#pragma unroll
        for (int i = 0; i < 2; i++) {
            const __bf16* rp = Ab + (size_t)(wr * 64 + i * 32 + fm) * 32;
            af[i][0] = *(const bf16x8*)(rp + slot0 * 8);
            af[i][1] = *(const bf16x8*)(rp + slot1 * 8);
        }
#pragma unroll
        for (int j = 0; j < 2; j++) {
            const __bf16* rp = Bb + (size_t)(wc * 64 + j * 32 + fm) * 32;
            bfv[j][0] = *(const bf16x8*)(rp + slot0 * 8);
            bfv[j][1] = *(const bf16x8*)(rp + slot1 * 8);
        }
#pragma unroll
        for (int t = 0; t < 2; t++)
#pragma unroll
            for (int i = 0; i < 2; i++)
#pragma unroll
                for (int j = 0; j < 2; j++)
                    acc[i][j] = __builtin_amdgcn_mfma_f32_32x32x16_bf16(
                        af[i][t], bfv[j][t], acc[i][j], 0, 0, 0);
    }
}

// ---------------------------------------------------------------------------
// Full-K GEMM with epilogue (used for W1). Grid: x = M-tiles, y = N-tiles.
// ---------------------------------------------------------------------------
template <typename OutT, bool BIAS, bool RELU, bool RES>
__global__ __launch_bounds__(256) void mgemm(const __bf16* __restrict__ A,
                                             const __bf16* __restrict__ Bt,
                                             const float* __restrict__ bias,
                                             const float* __restrict__ res,
                                             OutT* __restrict__ C,
                                             int M, int N, int Kstride, int Klen) {
    int tid = threadIdx.x;
    int lane = tid & 63;
    int wave = tid >> 6;
    int m0 = blockIdx.x * 128, n0 = blockIdx.y * 128;
    int wr = wave >> 1, wc = wave & 1;
    floatx16 acc[2][2] = {};
    mfma_core128(A, Bt, Kstride, Klen, m0, n0, tid, acc);

#pragma unroll
    for (int i = 0; i < 2; i++) {
#pragma unroll
        for (int j = 0; j < 2; j++) {
            int col  = n0 + wc * 64 + j * 32 + (lane & 31);
            int rowb = m0 + wr * 64 + i * 32 + 4 * (lane >> 5);
#pragma unroll
            for (int reg = 0; reg < 16; reg++) {
                int row = rowb + (reg & 3) + 8 * (reg >> 2);
                float v = acc[i][j][reg];
                if (BIAS) v += bias[col];
                if (RELU) v = fmaxf(v, 0.0f);
                if (RES)  v += res[(size_t)row * N + col];
                C[(size_t)row * N + col] = (OutT)v;
            }
        }
    }
}

// ---------------------------------------------------------------------------
// QKV GEMM: writes q,k parts to qkv[4096][3072]; v-part tiles are written
// ONLY as transposed Vt[bh][d][T] (8-byte t-runs) — vtrans kernel eliminated.
// ---------------------------------------------------------------------------
__global__ __launch_bounds__(256) void mgemm_qkv(const __bf16* __restrict__ A,
                                                 const __bf16* __restrict__ Bt,
                                                 __bf16* __restrict__ C,
                                                 __bf16* __restrict__ Vt) {
    const int N = 3072;
    int tid = threadIdx.x;
    int lane = tid & 63;
    int wave = tid >> 6;
    int m0 = blockIdx.x * 128, n0 = blockIdx.y * 128;
    int wr = wave >> 1, wc = wave & 1;
    floatx16 acc[2][2] = {};
    mfma_core128(A, Bt, 1024, 1024, m0, n0, tid, acc);

#pragma unroll
    for (int i = 0; i < 2; i++) {
#pragma unroll
        for (int j = 0; j < 2; j++) {
            int col  = n0 + wc * 64 + j * 32 + (lane & 31);
            int rowb = m0 + wr * 64 + i * 32 + 4 * (lane >> 5);
            if (col < 2048) {
#pragma unroll
                for (int reg = 0; reg < 16; reg++) {
                    int row = rowb + (reg & 3) + 8 * (reg >> 2);
                    C[(size_t)row * N + col] = (__bf16)acc[i][j][reg];
                }
            } else {
                int vcol = col - 2048;
                int hh = vcol >> 6, dd = vcol & 63;
#pragma unroll
                for (int rq = 0; rq < 4; rq++) {
                    int row0 = rowb + 8 * rq;
                    int bb = row0 >> 11;
                    int tt = row0 & 2047;
                    bf16x4 pack;
                    pack[0] = (__bf16)acc[i][j][4 * rq + 0];
                    pack[1] = (__bf16)acc[i][j][4 * rq + 1];
                    pack[2] = (__bf16)acc[i][j][4 * rq + 2];
                    pack[3] = (__bf16)acc[i][j][4 * rq + 3];
                    *(bf16x4*)&Vt[(((size_t)bb * 16 + hh) * 64 + dd) * SEQ + tt] = pack;
                }
            }
        }
    }
}

// ---------------------------------------------------------------------------
// Split-K GEMM: blockIdx.z picks K-chunk; writes bf16 partial tile.
// ---------------------------------------------------------------------------
__global__ __launch_bounds__(256) void mgemm_sk(const __bf16* __restrict__ A,
                                                const __bf16* __restrict__ Bt,
                                                __bf16* __restrict__ P0,
                                                __bf16* __restrict__ P3,
                                                int M, int N, int Kstride, int Klen) {
    int z = blockIdx.z;
    const __bf16* Az  = A  + (size_t)z * Klen;
    const __bf16* Btz = Bt + (size_t)z * Klen;
    __bf16* C = (z == 3) ? P3 : (P0 + (size_t)z * M * N);

    int tid = threadIdx.x;
    int lane = tid & 63;
    int wave = tid >> 6;
    int m0 = blockIdx.x * 128, n0 = blockIdx.y * 128;
    int wr = wave >> 1, wc = wave & 1;
    floatx16 acc[2][2] = {};
    mfma_core128(Az, Btz, Kstride, Klen, m0, n0, tid, acc);

#pragma unroll
    for (int i = 0; i < 2; i++) {
#pragma unroll
        for (int j = 0; j < 2; j++) {
            int col  = n0 + wc * 64 + j * 32 + (lane & 31);
            int rowb = m0 + wr * 64 + i * 32 + 4 * (lane >> 5);
#pragma unroll
            for (int reg = 0; reg < 16; reg++) {
                int row = rowb + (reg & 3) + 8 * (reg >> 2);
                C[(size_t)row * N + col] = (__bf16)acc[i][j][reg];
            }
        }
    }
}

// ---------------------------------------------------------------------------
// W2 reduction: out += p0+p1+p2+p3 + b2[col]  (in-place on out)
// ---------------------------------------------------------------------------
__global__ __launch_bounds__(256) void red_w2(const __bf16* __restrict__ p0,
                                              const __bf16* __restrict__ p3,
                                              const float* __restrict__ b2,
                                              float* __restrict__ out,
                                              int N) {
    size_t i = ((size_t)blockIdx.x * 256 + threadIdx.x) * 8;
    const size_t MN = (size_t)ROWS * HIDDEN;
    bf16x8 a = *(const bf16x8*)(p0 + i);
    bf16x8 b = *(const bf16x8*)(p0 + MN + i);
    bf16x8 c = *(const bf16x8*)(p0 + 2 * MN + i);
    bf16x8 d = *(const bf16x8*)(p3 + i);
    int col = (int)(i & (size_t)(N - 1));
    float4 bb0 = *(const float4*)(b2 + col);
    float4 bb1 = *(const float4*)(b2 + col + 4);
    float4 o0 = *(const float4*)(out + i);
    float4 o1 = *(const float4*)(out + i + 4);
    o0.x += (float)a[0] + (float)b[0] + (float)c[0] + (float)d[0] + bb0.x;
    o0.y += (float)a[1] + (float)b[1] + (float)c[1] + (float)d[1] + bb0.y;
    o0.z += (float)a[2] + (float)b[2] + (float)c[2] + (float)d[2] + bb0.z;
    o0.w += (float)a[3] + (float)b[3] + (float)c[3] + (float)d[3] + bb0.w;
    o1.x += (float)a[4] + (float)b[4] + (float)c[4] + (float)d[4] + bb1.x;
    o1.y += (float)a[5] + (float)b[5] + (float)c[5] + (float)d[5] + bb1.y;
    o1.z += (float)a[6] + (float)b[6] + (float)c[6] + (float)d[6] + bb1.z;
    o1.w += (float)a[7] + (float)b[7] + (float)c[7] + (float)d[7] + bb1.w;
    *(float4*)(out + i)     = o0;
    *(float4*)(out + i + 4) = o1;
}

// ---------------------------------------------------------------------------
// MFMA flash attention: no-max softmax, exp2, ones-MFMA l, and K/V register
// prefetch (kt+1 loads issued behind kt's compute).
// ---------------------------------------------------------------------------
__global__ __launch_bounds__(256) void attn_mfma(const __bf16* __restrict__ qkv,
                                                 const __bf16* __restrict__ Vt,
                                                 __bf16* __restrict__ ctx) {
    __shared__ __bf16 Ks[64 * 64];
    __shared__ __bf16 Vs[64 * 64];
    __shared__ __bf16 Ps[4][16 * 64];
    const int QKVW = 3 * HIDDEN;

    int bh = blockIdx.x;
    int qt = gridDim.y - 1 - blockIdx.y;   // heavy q-tiles dispatch first
    int b = bh >> 4, h = bh & 15;
    int tid = threadIdx.x;
    int lane = tid & 63;
    int w = tid >> 6;
    int m = lane & 15;
    int g = lane >> 4;

    const float QSC = 1.44269504f / 8.0f;
    bf16x8 qf[2];
    {
        const __bf16* Qp = qkv + (size_t)(b * SEQ + qt * 64 + w * 16 + m) * QKVW
                         + h * HDIM + g * 8;
        qf[0] = *(const bf16x8*)(Qp);
        qf[1] = *(const bf16x8*)(Qp + 32);
#pragma unroll
        for (int t = 0; t < 2; t++)
#pragma unroll
            for (int i = 0; i < 8; i++)
                qf[t][i] = (__bf16)((float)qf[t][i] * QSC);
    }

    bf16x8 onesf;
#pragma unroll
    for (int i = 0; i < 8; i++) onesf[i] = (__bf16)1.0f;

    floatx4 oacc[4] = {};
    floatx4 lacc = {};

    int srow = tid >> 2;
    int sc0  = (tid & 3) * 2;
    const __bf16* Kg = qkv + (size_t)(b * SEQ) * QKVW + HIDDEN + h * HDIM;
    const __bf16* Vg = Vt + (size_t)bh * HDIM * SEQ;

    // prefetch kt = 0
    bf16x8 pk0, pk1, pv0, pv1;
    {
        const __bf16* kp = Kg + (size_t)srow * QKVW + sc0 * 8;
        pk0 = *(const bf16x8*)kp;
        pk1 = *(const bf16x8*)(kp + 8);
        const __bf16* vp = Vg + (size_t)srow * SEQ + sc0 * 8;
        pv0 = *(const bf16x8*)vp;
        pv1 = *(const bf16x8*)(vp + 8);
    }

    for (int kt = 0; kt <= qt; kt++) {
        __syncthreads();   // prev compute's LDS reads done
        *(bf16x8*)&Ks[srow * 64 + SWZ(srow, sc0)]     = pk0;
        *(bf16x8*)&Ks[srow * 64 + SWZ(srow, sc0 + 1)] = pk1;
        *(bf16x8*)&Vs[srow * 64 + SWZ(srow, sc0)]     = pv0;
        *(bf16x8*)&Vs[srow * 64 + SWZ(srow, sc0 + 1)] = pv1;
        __syncthreads();

        if (kt < qt) {     // issue kt+1 loads; consumed next iteration
            const __bf16* kp = Kg + (size_t)((kt + 1) * 64 + srow) * QKVW + sc0 * 8;
            pk0 = *(const bf16x8*)kp;
            pk1 = *(const bf16x8*)(kp + 8);
            const __bf16* vp = Vg + (size_t)srow * SEQ + (kt + 1) * 64 + sc0 * 8;
            pv0 = *(const bf16x8*)vp;
            pv1 = *(const bf16x8*)(vp + 8);
        }

        floatx4 sacc[4] = {};
#pragma unroll
        for (int j = 0; j < 4; j++) {
#pragma unroll
            for (int t = 0; t < 2; t++) {
                int kr = 16 * j + m;
                bf16x8 kf = *(const bf16x8*)&Ks[kr * 64 + SWZ(kr, g + 4 * t)];
                sacc[j] = __builtin_amdgcn_mfma_f32_16x16x32_bf16(
                    qf[t], kf, sacc[j], 0, 0, 0);
            }
        }

        if (kt == qt) {
            int qlocal = w * 16 + 4 * g;
#pragma unroll
            for (int j = 0; j < 4; j++)
#pragma unroll
                for (int r = 0; r < 4; r++)
                    if (16 * j + m > qlocal + r) sacc[j][r] = -INFINITY;
        }

        __bf16* Pw = &Ps[w][0];
#pragma unroll
        for (int j = 0; j < 4; j++)
#pragma unroll
            for (int r = 0; r < 4; r++) {
                float p = exp2f(sacc[j][r]);
                int row = 4 * g + r;
                int key = 16 * j + m;
                Pw[row * 64 + SWZ(row, key >> 3) + (key & 7)] = (__bf16)p;
            }

#pragma unroll
        for (int t = 0; t < 2; t++) {
            bf16x8 pf = *(const bf16x8*)&Pw[m * 64 + SWZ(m, g + 4 * t)];
            lacc = __builtin_amdgcn_mfma_f32_16x16x32_bf16(pf, onesf, lacc, 0, 0, 0);
#pragma unroll
            for (int jd = 0; jd < 4; jd++) {
                int vr = 16 * jd + m;
                bf16x8 vf = *(const bf16x8*)&Vs[vr * 64 + SWZ(vr, g + 4 * t)];
                oacc[jd] = __builtin_amdgcn_mfma_f32_16x16x32_bf16(
                    pf, vf, oacc[jd], 0, 0, 0);
            }
        }
    }

#pragma unroll
    for (int r = 0; r < 4; r++) {
        float invl = 1.0f / lacc[r];
        int row = qt * 64 + w * 16 + 4 * g + r;
        __bf16* cp = ctx + (size_t)(b * SEQ + row) * HIDDEN + h * HDIM;
#pragma unroll
        for (int jd = 0; jd < 4; jd++)
            cp[16 * jd + m] = (__bf16)(oacc[jd][r] * invl);
    }
}

// ---------------------------------------------------------------------------
extern "C" void kernel_launch(void* const* d_in, const int* in_sizes, int n_in,
                              void* d_out, int out_size, void* d_ws, size_t ws_size,
                              hipStream_t stream) {
    (void)in_sizes; (void)n_in; (void)out_size; (void)ws_size;
    const float* emb = (const float*)d_in[0];
    const float* Wq  = (const float*)d_in[1];
    const float* Wk  = (const float*)d_in[2];
    const float* Wv  = (const float*)d_in[3];
    const float* Wo  = (const float*)d_in[4];
    const float* W1  = (const float*)d_in[5];
    const float* b1  = (const float*)d_in[6];
    const float* W2  = (const float*)d_in[7];
    const float* b2  = (const float*)d_in[8];
    const float* g1  = (const float*)d_in[9];
    const float* be1 = (const float*)d_in[10];
    const float* g2  = (const float*)d_in[11];
    const float* be2 = (const float*)d_in[12];
    float* out = (float*)d_out;

    // ws layout (bf16 elems; ME = 1M elems = 2MB). Total 36 ME = 72 MB.
    //   [0,4)   h (LN1) -> ctx (attn out)
    //   [4,16)  qkv (q,k used; v-part unwritten) -> Wo partials [4,12)
    //   [0,16)  ff1 (after red_wo_ln)
    //   [16,20) h2 -> W2 partial z0
    //   [20,24) BtQKV+BtO -> W2 partial z1
    //   [24,28) Bt1 -> W2 partial z2
    //   [28,32) Bt2 (alive through W2 gemm)
    //   [32,36) Vt (dead after attn) -> W2 partial z3
    __bf16* wsb = (__bf16*)d_ws;
    const size_t ME = 1024 * 1024;
    __bf16* h     = wsb;
    __bf16* qkv   = wsb + 4 * ME;
    __bf16* ctx   = wsb;
    __bf16* ff1   = wsb;
    __bf16* h2    = wsb + 16 * ME;
    __bf16* BtQKV = wsb + 20 * ME;
    __bf16* BtO   = wsb + 23 * ME;
    __bf16* Bt1   = wsb + 24 * ME;
    __bf16* Bt2   = wsb + 28 * ME;
    __bf16* Vt    = wsb + 32 * ME;
    __bf16* woP   = wsb + 4 * ME;    // 2 x 4 ME
    __bf16* w2P0  = wsb + 16 * ME;   // z0..z2 contiguous (12 ME)
    __bf16* w2P3  = wsb + 32 * ME;   // z3

    // weight converts + LN1 in one launch
    prep_all<<<16384, 256, 0, stream>>>(Wq, Wk, Wv, Wo, W1, W2,
                                        BtQKV, BtO, Bt1, Bt2,
                                        emb, g1, be1, h);

    // QKV GEMM; v-part emitted directly as Vt (transposed)
    mgemm_qkv<<<dim3(32, 24), 256, 0, stream>>>(h, BtQKV, qkv, Vt);

    attn_mfma<<<dim3(32, 32), 256, 0, stream>>>(qkv, Vt, ctx);

    // Wo split-K x2
    mgemm_sk<<<dim3(32, 8, 2), 256, 0, stream>>>(
        ctx, BtO, woP, nullptr, ROWS, 1024, 1024, 512);
    red_wo_ln<<<ROWS, 256, 0, stream>>>(emb, woP, woP + 4 * ME, g2, be2, out, h2);

    mgemm<__bf16, true, true, false><<<dim3(32, 32), 256, 0, stream>>>(
        h2, Bt1, b1, nullptr, ff1, ROWS, 4096, 1024, 1024);

    // W2 split-K x4
    mgemm_sk<<<dim3(32, 8, 4), 256, 0, stream>>>(
        ff1, Bt2, w2P0, w2P3, ROWS, 1024, 4096, 1024);
    red_w2<<<2048, 256, 0, stream>>>(w2P0, w2P3, b2, out, 1024);
}